// Round 5
// baseline (7307.630 us; speedup 1.0000x reference)
//
#include <hip/hip_runtime.h>
#include <cstdint>
#include <cstddef>

// Problem constants
#define B_SZ 512
#define S_SZ 120
#define D_SZ 216
#define H_SZ 1024
#define NG   4096     // 4*H
#define DP   256      // D padded
#define TMAX 24

// GEMM tile config: block 64(M) x 128(N), BK=64, 4 waves 1x4 (wave = 64M x 32N)
#define BM 64
#define BN 128
#define BK 64

using bf16_t = __bf16;
using bf16x8 = __attribute__((ext_vector_type(8))) __bf16;
using f32x4  = __attribute__((ext_vector_type(4))) float;

__device__ __forceinline__ void gload16(const void* g, void* l) {
  __builtin_amdgcn_global_load_lds(
      (const __attribute__((address_space(1))) void*)g,
      (__attribute__((address_space(3))) void*)l, 16, 0, 0);
}

__device__ __forceinline__ float fsigmoid(float x) {
  x = fminf(fmaxf(x, -30.f), 30.f);
  return 1.f / (1.f + __expf(-x));
}
__device__ __forceinline__ float ftanh(float x) {
  x = fminf(fmaxf(x, -15.f), 15.f);
  float e = __expf(2.f * x);
  return (e - 1.f) / (e + 1.f);
}

// LDS: two A-staging buffers (6 segs x 64 rows x 128 B = 48 KB each).
// A stored [seg][row][128B] with XOR 16B-chunk swizzle on the GLOBAL side:
// LDS slot (row, c) holds global chunk c ^ (row&7). gate[] unions over buf1.
struct __align__(16) Smem {
  union {
    bf16_t bufs[2][6 * 64 * 64];                      // 2 x 49152 B
    struct { char pad[49152]; float gate[64 * 129]; } g;
  };
};

// Weight swizzled layout ("fragment-major"): for frag (nb = n>>4, kb = k>>5):
// chunk lane l = ((k>>3)&3)*16 + (n&15), 8 k-contiguous bf16 per lane.
// flat 16B-chunk id = (nb*KB + kb)*64 + l, KB = K/32.

// ============================================================================
// Persistent kernel: all 144 LSTM steps in one launch.
// Grid dim3(32, 8): x = n-tile (128 gate cols), y = m-group (64 batch rows).
// Dependency: block (x,y) step s needs h rows y*64..+63, ALL cols -> produced
// by the 32 blocks with same y. Per-(step,group) arrival counters in bars[].
// All 256 blocks co-resident (1 block/CU via 96KB LDS + launch_bounds).
// ============================================================================
__global__ __launch_bounds__(256, 1) void lstm_persist(
    const bf16_t* __restrict__ srcbf,   // (S, B, DP) bf16
    const bf16_t* __restrict__ WcatSw,  // swizzled, KB=40 (src kb 0..7, h kb 8..39)
    const bf16_t* __restrict__ WdecSw,  // swizzled, KB=32
    const float* __restrict__ biasE,
    const float* __restrict__ biasD,
    bf16_t* __restrict__ hP0, bf16_t* __restrict__ hP1,
    bf16_t* __restrict__ Hs,            // (TMAX, B, H) decoder h outputs
    int* __restrict__ bars)             // [144][8] arrival counters (zeroed)
{
  __shared__ Smem sm;
  const int t    = threadIdx.x;
  const int nt   = blockIdx.x;       // n-tile 0..31
  const int gI   = blockIdx.y;       // m-group 0..7
  const int m0   = gI * BM;
  const int n0   = nt * BN;
  const int lane = t & 63;
  const int wv   = t >> 6;
  const int fr   = lane & 15;
  const int fq   = lane >> 4;
  const int u0   = n0 >> 2;
  const size_t BH = (size_t)B_SZ * H_SZ;

  // Bias registers (both variants)
  float bE[2], bD[2];
#pragma unroll
  for (int nj = 0; nj < 2; ++nj) {
    int col = n0 + wv * 32 + nj * 16 + fr;
    bE[nj] = biasE[col];
    bD[nj] = biasD[col];
  }

  // Cell state in registers: thread t owns (row = itc*8 + (t>>5), unit u0+(t&31))
  float creg[8];
#pragma unroll
  for (int i = 0; i < 8; ++i) creg[i] = 0.f;

  const int nb0  = (n0 >> 4) + wv * 2;
  const int row8 = t >> 3;
  const int c16s = t & 7;

  // A staging with XOR swizzle; LDS dest is wave-uniform base + lane*16.
  auto stageA = [&](const bf16_t* Ap, int sA, int buf, int k0, int nseg) {
    char* base = (char*)&sm.bufs[0][0] + buf * 49152;
#pragma unroll
    for (int half = 0; half < 2; ++half) {
      int row = half * 32 + row8;
      int gc  = (c16s ^ (row & 7)) * 8;
      const bf16_t* ga = Ap + (size_t)(m0 + row) * sA + k0 + gc;
      char* ldst = base + (half * 32 + wv * 8) * 128;
      for (int seg = 0; seg < nseg; ++seg)
        gload16(ga + seg * 64, ldst + seg * 8192);
    }
  };

  for (int s = 0; s < 144; ++s) {
    const bool enc = (s <= 120);
    const int  KBs = enc ? 40 : 32;
    const bf16_t* Wb0 = (enc ? WcatSw : WdecSw) + (size_t)nb0 * KBs * 512;
    const bf16_t* Wb1 = Wb0 + (size_t)KBs * 512;
    const float*  b2  = enc ? bE : bD;
    bf16_t* hw = (s < 120) ? ((s & 1) ? hP1 : hP0) : Hs + (size_t)(s - 120) * BH;
    const bf16_t* hr = (s == 0) ? nullptr
                     : (s - 1 < 120) ? (((s - 1) & 1) ? hP1 : hP0)
                                     : Hs + (size_t)(s - 1 - 120) * BH;

    f32x4 acc[4][2] = {};
    bf16x8 Bv[2][4];

    auto loadB = [&](int kb, bf16x8* B) {
      B[0] = *(const bf16x8*)(Wb0 + (size_t)kb * 512 + lane * 8);
      B[1] = *(const bf16x8*)(Wb0 + (size_t)(kb + 1) * 512 + lane * 8);
      B[2] = *(const bf16x8*)(Wb1 + (size_t)kb * 512 + lane * 8);
      B[3] = *(const bf16x8*)(Wb1 + (size_t)(kb + 1) * 512 + lane * 8);
    };
    auto compute = [&](int buf, int seg, const bf16x8* B) {
      const char* base = (const char*)&sm.bufs[0][0] + buf * 49152 + seg * 8192;
#pragma unroll
      for (int kk = 0; kk < 2; ++kk)
#pragma unroll
        for (int mi = 0; mi < 4; ++mi) {
          int row = mi * 16 + fr;
          bf16x8 av = *(const bf16x8*)(base + row * 128 +
                                       (((kk * 4 + fq) ^ (row & 7)) * 16));
          acc[mi][0] = __builtin_amdgcn_mfma_f32_16x16x32_bf16(av, B[kk],     acc[mi][0], 0, 0, 0);
          acc[mi][1] = __builtin_amdgcn_mfma_f32_16x16x32_bf16(av, B[2 + kk], acc[mi][1], 0, 0, 0);
        }
    };

    int it = 0;  // global K-iter; kb = 2*it in both layouts
    if (enc) {
      // src part: no dependency on h -> runs before the barrier wait
      int xi = (s <= 119) ? s : 119;
      const bf16_t* As = srcbf + (size_t)xi * B_SZ * DP;
      stageA(As, DP, 0, 0, 4);
      loadB(0, Bv[0]);
      __syncthreads();
#pragma unroll
      for (int i = 0; i < 4; ++i, ++it) {
        loadB(2 * (it + 1), Bv[(it + 1) & 1]);   // it=3 prefetches h iter 0
        compute(0, i, Bv[it & 1]);
      }
    }
    if (s > 0) {
      // Wait for all 32 blocks of this m-group to finish step s-1's h.
      if (t == 0) {
        while (__hip_atomic_load(&bars[(s - 1) * 8 + gI], __ATOMIC_RELAXED,
                                 __HIP_MEMORY_SCOPE_AGENT) < 32)
          __builtin_amdgcn_s_sleep(2);
      }
      __syncthreads();
      __threadfence();   // acquire: fresh h across XCD/L1
      // h part: 16 iters, chunks 6(buf1) / 6(buf0) / 4(buf1)
      stageA(hr, H_SZ, 1, 0, 6);
      __syncthreads();
      stageA(hr, H_SZ, 0, 384, 6);
      if (!enc) loadB(2 * it, Bv[it & 1]);
#pragma unroll
      for (int i = 0; i < 6; ++i, ++it) {
        loadB(2 * (it + 1), Bv[(it + 1) & 1]);
        compute(1, i, Bv[it & 1]);
      }
      __syncthreads();
      stageA(hr, H_SZ, 1, 768, 4);
#pragma unroll
      for (int i = 0; i < 6; ++i, ++it) {
        loadB(2 * (it + 1), Bv[(it + 1) & 1]);
        compute(0, i, Bv[it & 1]);
      }
      __syncthreads();
#pragma unroll
      for (int i = 0; i < 4; ++i, ++it) {
        if (i < 3) loadB(2 * (it + 1), Bv[(it + 1) & 1]);
        compute(1, i, Bv[it & 1]);
      }
    }

    // ---- epilogue: gates -> LDS (over buf1), cell math, write h ----
    __syncthreads();
#pragma unroll
    for (int mi = 0; mi < 4; ++mi)
#pragma unroll
      for (int nj = 0; nj < 2; ++nj)
#pragma unroll
        for (int v = 0; v < 4; ++v) {
          int row = mi * 16 + fq * 4 + v;
          int col = wv * 32 + nj * 16 + fr;
          sm.g.gate[row * 129 + col] = acc[mi][nj][v] + b2[nj];
        }
    __syncthreads();
#pragma unroll
    for (int itc = 0; itc < 8; ++itc) {
      int brw = itc * 8 + (t >> 5);
      int ju  = t & 31;
      const float* gp = &sm.g.gate[brw * 129 + ju * 4];
      float iv = fsigmoid(gp[0]);
      float fv = fsigmoid(gp[1]);
      float gv = ftanh(gp[2]);
      float ov = fsigmoid(gp[3]);
      float cn = fv * creg[itc] + iv * gv;
      creg[itc] = cn;
      hw[(size_t)(m0 + brw) * H_SZ + (u0 + ju)] = (bf16_t)(ov * ftanh(cn));
    }
    __threadfence();   // release this thread's h stores to agent scope
    __syncthreads();
    if (t == 0)
      __hip_atomic_fetch_add(&bars[s * 8 + gI], 1, __ATOMIC_RELAXED,
                             __HIP_MEMORY_SCOPE_AGENT);
  }
}

// ============================================================================
// One-shot GEMM kernel (Wdec build + final projection), from round 4.
// ============================================================================
template <int EPI, int N1, int N2>
__global__ __launch_bounds__(256, 1) void gemm_step(
    const bf16_t* __restrict__ A1, int sA1,
    const bf16_t* __restrict__ A2, int sA2,
    const bf16_t* __restrict__ Wsw,
    const float* __restrict__ bias,
    const float* __restrict__ addm, bf16_t* __restrict__ outb,
    float* __restrict__ outf)
{
  constexpr int NTOT = N1 + N2;
  constexpr int KB   = NTOT * 2;
  constexpr int C0 = NTOT < 4 ? NTOT : 4;
  constexpr int R0 = NTOT - C0;
  constexpr int C1 = R0 < 6 ? R0 : 6;
  constexpr int R1 = R0 - C1;
  constexpr int C2 = R1 < 6 ? R1 : 6;
  constexpr int C3 = R1 - C2;
  static_assert(C3 <= 6, "chunk overflow");

  __shared__ Smem sm;
  const int t    = threadIdx.x;
  const int m0   = blockIdx.y * BM;
  const int n0   = blockIdx.x * BN;
  const int lane = t & 63;
  const int wv   = t >> 6;
  const int fr   = lane & 15;
  const int fq   = lane >> 4;

  f32x4 acc[4][2] = {};

  float bias2[2] = {0.f, 0.f};
  if (EPI == 3) {
#pragma unroll
    for (int nj = 0; nj < 2; ++nj) {
      int col = n0 + wv * 32 + nj * 16 + fr;
      bias2[nj] = (col >= D_SZ) ? 0.f : bias[col];
    }
  }

  auto stageChunk = [&](int ci, int kst, int csz) {
    const bf16_t* Ap; int sA; int kloc;
    if (ci == 0 && N1 > 0) { Ap = A1; sA = sA1; kloc = 0; }
    else                   { Ap = A2; sA = sA2; kloc = kst - N1 * BK; }
    char* base = (char*)&sm.bufs[ci & 1][0];
    const int row8 = t >> 3;
    const int c16s = (t & 7);
#pragma unroll
    for (int half = 0; half < 2; ++half) {
      int row = half * 32 + row8;
      int gc  = (c16s ^ (row & 7)) * 8;
      const bf16_t* ga = Ap + (size_t)(m0 + row) * sA + kloc + gc;
      char* ldst = base + (half * 32 + wv * 8) * 128;
      for (int seg = 0; seg < csz; ++seg)
        gload16(ga + seg * 64, ldst + seg * 8192);
    }
  };

  const int nb0 = (n0 >> 4) + wv * 2;
  auto loadB = [&](int itq, bf16x8* Bv) {
#pragma unroll
    for (int nj = 0; nj < 2; ++nj)
#pragma unroll
      for (int kk = 0; kk < 2; ++kk)
        Bv[nj * 2 + kk] = *(const bf16x8*)((const char*)Wsw +
            ((size_t)((nb0 + nj) * KB + itq * 2 + kk) * 64 + lane) * 16);
  };

  auto compute = [&](const bf16x8* Bv, int bufi, int seg) {
    const char* base = (const char*)&sm.bufs[bufi][0] + seg * 8192;
#pragma unroll
    for (int kk = 0; kk < 2; ++kk)
#pragma unroll
      for (int mi = 0; mi < 4; ++mi) {
        int row = mi * 16 + fr;
        bf16x8 av = *(const bf16x8*)(base + row * 128 +
                                     (((kk * 4 + fq) ^ (row & 7)) * 16));
        acc[mi][0] = __builtin_amdgcn_mfma_f32_16x16x32_bf16(av, Bv[kk],     acc[mi][0], 0, 0, 0);
        acc[mi][1] = __builtin_amdgcn_mfma_f32_16x16x32_bf16(av, Bv[2 + kk], acc[mi][1], 0, 0, 0);
      }
  };

  bf16x8 Bv[2][4];
  loadB(0, Bv[0]);
  stageChunk(0, 0, C0);
  __syncthreads();
  if (C1 > 0) stageChunk(1, C0 * BK, C1);
#pragma unroll
  for (int i = 0; i < C0; ++i) {
    if (i + 1 < NTOT) loadB(i + 1, Bv[(i + 1) & 1]);
    compute(Bv[i & 1], 0, i);
  }
  if (C1 > 0) {
    __syncthreads();
    if (C2 > 0) stageChunk(2, (C0 + C1) * BK, C2);
#pragma unroll
    for (int i = 0; i < C1; ++i) {
      int itq = C0 + i;
      if (itq + 1 < NTOT) loadB(itq + 1, Bv[(itq + 1) & 1]);
      compute(Bv[itq & 1], 1, i);
    }
  }
  if (C2 > 0) {
    __syncthreads();
    if (C3 > 0) stageChunk(3, (C0 + C1 + C2) * BK, C3);
#pragma unroll
    for (int i = 0; i < C2; ++i) {
      int itq = C0 + C1 + i;
      if (itq + 1 < NTOT) loadB(itq + 1, Bv[(itq + 1) & 1]);
      compute(Bv[itq & 1], 0, i);
    }
  }
  if (C3 > 0) {
    __syncthreads();
#pragma unroll
    for (int i = 0; i < C3; ++i) {
      int itq = C0 + C1 + C2 + i;
      if (itq + 1 < NTOT) loadB(itq + 1, Bv[(itq + 1) & 1]);
      compute(Bv[itq & 1], 1, i);
    }
  }
  __syncthreads();

  if (EPI == 2) {
#pragma unroll
    for (int mi = 0; mi < 4; ++mi)
#pragma unroll
      for (int nj = 0; nj < 2; ++nj)
#pragma unroll
        for (int v = 0; v < 4; ++v) {
          int row = mi * 16 + fq * 4 + v;
          int col = wv * 32 + nj * 16 + fr;
          int gr = m0 + row, gc = n0 + col;
          int orig = (gr & 3) * H_SZ + (gr >> 2);
          sm.g.gate[row * 129 + col] = acc[mi][nj][v] + addm[(size_t)orig * H_SZ + gc];
        }
    __syncthreads();
#pragma unroll
    for (int q = 0; q < 4; ++q) {
      int c = q * 256 + t;
      int nbl = c >> 8, kbl = (c >> 6) & 3, l2 = c & 63;
      int nloc = nbl * 16 + (l2 & 15);
      int kloc = kbl * 32 + (l2 >> 4) * 8;
      const float* gp = &sm.g.gate[nloc * 129 + kloc];
      bf16x8 v;
#pragma unroll
      for (int j = 0; j < 8; ++j) v[j] = (bf16_t)gp[j];
      size_t chunk = (size_t)(((m0 >> 4) + nbl) * 32 + (n0 >> 5) + kbl) * 64 + l2;
      *(bf16x8*)(outb + chunk * 8) = v;
    }
  }

  if (EPI == 3) {
#pragma unroll
    for (int mi = 0; mi < 4; ++mi)
#pragma unroll
      for (int nj = 0; nj < 2; ++nj)
#pragma unroll
        for (int v = 0; v < 4; ++v) {
          int m = m0 + mi * 16 + fq * 4 + v;
          int n = n0 + wv * 32 + nj * 16 + fr;
          if (n < D_SZ) {
            outf[((size_t)(m & 511) * TMAX + (m >> 9)) * D_SZ + n] =
                acc[mi][nj][v] + bias2[nj];
          }
        }
  }
}

// src (B,S,D) fp32 -> srcbf (S,B,DP) bf16, zero-padded
__global__ void k_convert_src(const float* __restrict__ src, bf16_t* __restrict__ dst) {
  int idx = blockIdx.x * 256 + threadIdx.x;
  int total = S_SZ * B_SZ * DP;
  if (idx >= total) return;
  int d = idx % DP;
  int r = idx / DP;
  int b = r % B_SZ;
  int tt = r / B_SZ;
  float v = (d < D_SZ) ? src[((size_t)b * S_SZ + tt) * D_SZ + d] : 0.f;
  dst[idx] = (bf16_t)v;
}

// Swizzled W_cat (N=4096 gate-interleaved rows, K=1280: [Wih|0|Whh]), KB=40
__global__ void k_build_wcat_sw(const float* __restrict__ Wih, const float* __restrict__ Whh,
                                bf16_t* __restrict__ out) {
  int c = blockIdx.x * 256 + threadIdx.x;
  if (c >= 256 * 40 * 64) return;
  int l = c & 63;
  int kb = (c >> 6) % 40;
  int nb = c / (40 * 64);
  int n = nb * 16 + (l & 15);
  int k0 = kb * 32 + (l >> 4) * 8;
  int o = (n & 3) * H_SZ + (n >> 2);
  bf16x8 v;
#pragma unroll
  for (int j = 0; j < 8; ++j) {
    int k = k0 + j;
    float x = (k < D_SZ) ? Wih[(size_t)o * D_SZ + k]
            : (k < DP ? 0.f : Whh[(size_t)o * H_SZ + (k - DP)]);
    v[j] = (bf16_t)x;
  }
  *(bf16x8*)(out + (size_t)c * 8) = v;
}

// Swizzled B for Wdec build: B[n=h][k=d] = Wout[d][h], KB=8
__global__ void k_build_woutt_sw(const float* __restrict__ Wout, bf16_t* __restrict__ out) {
  int c = blockIdx.x * 256 + threadIdx.x;
  if (c >= 64 * 8 * 64) return;
  int l = c & 63;
  int kb = (c >> 6) % 8;
  int nb = c / (8 * 64);
  int n = nb * 16 + (l & 15);
  int k0 = kb * 32 + (l >> 4) * 8;
  bf16x8 v;
#pragma unroll
  for (int j = 0; j < 8; ++j) {
    int k = k0 + j;
    v[j] = (bf16_t)((k < D_SZ) ? Wout[(size_t)k * H_SZ + n] : 0.f);
  }
  *(bf16x8*)(out + (size_t)c * 8) = v;
}

// Swizzled B for final projection: B[n=d][k=h] = Wout[d][h], KB=32
__global__ void k_build_wout_sw(const float* __restrict__ Wout, bf16_t* __restrict__ out) {
  int c = blockIdx.x * 256 + threadIdx.x;
  if (c >= 16 * 32 * 64) return;
  int l = c & 63;
  int kb = (c >> 6) % 32;
  int nb = c / (32 * 64);
  int n = nb * 16 + (l & 15);
  int k0 = kb * 32 + (l >> 4) * 8;
  bf16x8 v;
#pragma unroll
  for (int j = 0; j < 8; ++j)
    v[j] = (bf16_t)((n < D_SZ) ? Wout[(size_t)n * H_SZ + k0 + j] : 0.f);
  *(bf16x8*)(out + (size_t)c * 8) = v;
}

// Natural A for Wdec build: [4096 gate rows][256 d-pad] bf16
__global__ void k_build_wihre(const float* __restrict__ Wih, bf16_t* __restrict__ out) {
  int c = blockIdx.x * 256 + threadIdx.x;
  if (c >= 4096 * 32) return;
  int r = c >> 5;
  int k0 = (c & 31) * 8;
  int o = (r & 3) * H_SZ + (r >> 2);
  bf16x8 v;
#pragma unroll
  for (int j = 0; j < 8; ++j) {
    int k = k0 + j;
    v[j] = (bf16_t)((k < D_SZ) ? Wih[(size_t)o * D_SZ + k] : 0.f);
  }
  *(bf16x8*)(out + (size_t)c * 8) = v;
}

// bias_enc[r] = b_ih[o]+b_hh[o];  bias_dec[r] = bias_enc[r] + W_ih[o,:].b_out
__global__ void k_build_bias(const float* __restrict__ bih, const float* __restrict__ bhh,
                             const float* __restrict__ Wih, const float* __restrict__ bout,
                             float* __restrict__ biasE, float* __restrict__ biasD) {
  int r = blockIdx.x * 256 + threadIdx.x;
  if (r >= NG) return;
  int o = (r & 3) * H_SZ + (r >> 2);
  float be = bih[o] + bhh[o];
  biasE[r] = be;
  float s = 0.f;
  const float* wr = Wih + (size_t)o * D_SZ;
  for (int d = 0; d < D_SZ; ++d) s += wr[d] * bout[d];
  biasD[r] = be + s;
}

extern "C" void kernel_launch(void* const* d_in, const int* in_sizes, int n_in,
                              void* d_out, int out_size, void* d_ws, size_t ws_size,
                              hipStream_t stream) {
  const float* src  = (const float*)d_in[0];
  const float* Wih  = (const float*)d_in[1];
  const float* Whh  = (const float*)d_in[2];
  const float* bih  = (const float*)d_in[3];
  const float* bhh  = (const float*)d_in[4];
  const float* Wout = (const float*)d_in[5];
  const float* bout = (const float*)d_in[6];

  char* ws = (char*)d_ws;
  size_t off = 0;
  auto alloc = [&](size_t bytes) {
    void* p = ws + off;
    off = (off + bytes + 255) & ~(size_t)255;
    return p;
  };
  bf16_t* srcbf  = (bf16_t*)alloc((size_t)S_SZ * B_SZ * DP * 2);   // 31.5 MB
  bf16_t* WcatSw = (bf16_t*)alloc((size_t)256 * 40 * 64 * 16);     // 10.5 MB
  bf16_t* WdecSw = (bf16_t*)alloc((size_t)NG * H_SZ * 2);          //  8.4 MB
  bf16_t* WouttSw= (bf16_t*)alloc((size_t)64 * 8 * 64 * 16);
  bf16_t* WoutSw = (bf16_t*)alloc((size_t)16 * 32 * 64 * 16);
  bf16_t* WihRe  = (bf16_t*)alloc((size_t)NG * DP * 2);            //  2 MB
  float*  biasE  = (float*)alloc((size_t)NG * 4);
  float*  biasD  = (float*)alloc((size_t)NG * 4);
  bf16_t* hP0    = (bf16_t*)alloc((size_t)B_SZ * H_SZ * 2);
  bf16_t* hP1    = (bf16_t*)alloc((size_t)B_SZ * H_SZ * 2);
  bf16_t* Hs     = (bf16_t*)alloc((size_t)TMAX * B_SZ * H_SZ * 2); // 25.2 MB
  int*    bars   = (int*)alloc((size_t)144 * 8 * 4);

  hipMemsetAsync(bars, 0, (size_t)144 * 8 * 4, stream);

  k_convert_src<<<(S_SZ * B_SZ * DP + 255) / 256, 256, 0, stream>>>(src, srcbf);
  k_build_wcat_sw<<<(256 * 40 * 64 + 255) / 256, 256, 0, stream>>>(Wih, Whh, WcatSw);
  k_build_woutt_sw<<<(64 * 8 * 64 + 255) / 256, 256, 0, stream>>>(Wout, WouttSw);
  k_build_wout_sw<<<(16 * 32 * 64 + 255) / 256, 256, 0, stream>>>(Wout, WoutSw);
  k_build_wihre<<<(4096 * 32 + 255) / 256, 256, 0, stream>>>(Wih, WihRe);
  k_build_bias<<<(NG + 255) / 256, 256, 0, stream>>>(bih, bhh, Wih, bout, biasE, biasD);

  // W_dec(swizzled) = Whh_reord + Wih_reord @ Wout  (M=4096, N=1024, K=256)
  gemm_step<2, 4, 0><<<dim3(H_SZ / BN, NG / BM), 256, 0, stream>>>(
      WihRe, DP, nullptr, 0, WouttSw, nullptr, Whh, WdecSw, nullptr);

  // All 144 recurrent steps in one persistent kernel.
  lstm_persist<<<dim3(32, 8), 256, 0, stream>>>(
      srcbf, WcatSw, WdecSw, biasE, biasD, hP0, hP1, Hs, bars);

  // Final projection: Y(12288 x 216) = Hs(12288 x 1024) @ Wout^T + b_out
  gemm_step<3, 0, 16><<<dim3(2, (TMAX * B_SZ) / BM), 256, 0, stream>>>(
      nullptr, 0, Hs, H_SZ, WoutSw, bout, nullptr, nullptr, (float*)d_out);
}

// Round 6
// 2779.920 us; speedup vs baseline: 2.6287x; 2.6287x over previous
//
#include <hip/hip_runtime.h>
#include <cstdint>
#include <cstddef>

// Problem constants
#define B_SZ 512
#define S_SZ 120
#define D_SZ 216
#define H_SZ 1024
#define NG   4096     // 4*H
#define DP   256      // D padded
#define TMAX 24

// GEMM tile config: block 64(M) x 128(N), BK=64, 4 waves 1x4 (wave = 64M x 32N)
#define BM 64
#define BN 128
#define BK 64

using bf16_t = __bf16;
using bf16x8 = __attribute__((ext_vector_type(8))) __bf16;
using f32x4  = __attribute__((ext_vector_type(4))) float;

template <int A> struct Aux { static constexpr int v = A; };

// aux: cache-policy bits (gfx950: SC0=1, NT=2, SC1=16). SC1 = device-scope,
// bypasses the (potentially stale, non-coherent) local XCD L2 -- used ONLY
// for cross-block h reads so weights stay L2-resident.
template <int AUX>
__device__ __forceinline__ void gload16(const void* g, void* l) {
  __builtin_amdgcn_global_load_lds(
      (const __attribute__((address_space(1))) void*)g,
      (__attribute__((address_space(3))) void*)l, 16, 0, AUX);
}

__device__ __forceinline__ float fsigmoid(float x) {
  x = fminf(fmaxf(x, -30.f), 30.f);
  return 1.f / (1.f + __expf(-x));
}
__device__ __forceinline__ float ftanh(float x) {
  x = fminf(fmaxf(x, -15.f), 15.f);
  float e = __expf(2.f * x);
  return (e - 1.f) / (e + 1.f);
}

// LDS: two A-staging buffers (6 segs x 64 rows x 128 B = 48 KB each).
// A stored [seg][row][128B] with XOR 16B-chunk swizzle on the GLOBAL side:
// LDS slot (row, c) holds global chunk c ^ (row&7). gate[] unions over buf1.
// gate stride 132 floats = 528 B (16B-aligned rows -> float4 reads are
// ds_read_b128, 2-way bank aliasing = free).
struct __align__(16) Smem {
  union {
    bf16_t bufs[2][6 * 64 * 64];                      // 2 x 49152 B
    struct { char pad[49152]; float gate[64 * 132]; } g;
  };
};

// Weight swizzled layout ("fragment-major"): for frag (nb = n>>4, kb = k>>5):
// chunk lane l = ((k>>3)&3)*16 + (n&15), 8 k-contiguous bf16 per lane.
// flat 16B-chunk id = (nb*KB + kb)*64 + l, KB = K/32.

// ============================================================================
// Persistent kernel: all 144 LSTM steps in one launch.
// Grid dim3(32, 8): x = n-tile (128 gate cols), y = m-group (64 batch rows).
// Block (x,y) at step s needs h rows y*64..+63 (all cols) = outputs of the 32
// blocks sharing y. Sync: per-(step,group) arrival counters, RELEASE atomics
// (emits s_waitcnt+buffer_wbl2: write-back only -- weights stay in L2; the
// round-5 __threadfence() emitted buffer_inv and flushed 5 MB/step -> 718 MB
// HBM refetch). Consumers re-read h with SC1 loads (bypass stale local L2).
// All 256 blocks co-resident (1 block/CU via 96KB LDS + launch_bounds).
// ============================================================================
__global__ __launch_bounds__(256, 1) void lstm_persist(
    const bf16_t* __restrict__ srcbf,   // (S, B, DP) bf16
    const bf16_t* __restrict__ WcatSw,  // swizzled, KB=40 (src kb 0..7, h kb 8..39)
    const bf16_t* __restrict__ WdecSw,  // swizzled, KB=32
    const float* __restrict__ biasE,
    const float* __restrict__ biasD,
    bf16_t* __restrict__ hP0, bf16_t* __restrict__ hP1,
    bf16_t* __restrict__ Hs,            // (TMAX, B, H) decoder h outputs
    int* __restrict__ bars)             // [144][8] arrival counters (zeroed)
{
  __shared__ Smem sm;
  const int t    = threadIdx.x;
  const int nt   = blockIdx.x;       // n-tile 0..31
  const int gI   = blockIdx.y;       // m-group 0..7
  const int m0   = gI * BM;
  const int n0   = nt * BN;
  const int lane = t & 63;
  const int wv   = t >> 6;
  const int fr   = lane & 15;
  const int fq   = lane >> 4;
  const int u0   = n0 >> 2;
  const size_t BH = (size_t)B_SZ * H_SZ;

  // Bias registers (both variants)
  float bE[2], bD[2];
#pragma unroll
  for (int nj = 0; nj < 2; ++nj) {
    int col = n0 + wv * 32 + nj * 16 + fr;
    bE[nj] = biasE[col];
    bD[nj] = biasD[col];
  }

  // Cell state in registers: thread t owns (row = itc*8 + (t>>5), unit u0+(t&31))
  float creg[8];
#pragma unroll
  for (int i = 0; i < 8; ++i) creg[i] = 0.f;

  const int nb0  = (n0 >> 4) + wv * 2;
  const int row8 = t >> 3;
  const int c16s = t & 7;

  // A staging with XOR swizzle; LDS dest is wave-uniform base + lane*16.
  auto stageA = [&](auto aux, const bf16_t* Ap, int sA, int buf, int k0, int nseg) {
    constexpr int AUX = decltype(aux)::v;
    char* base = (char*)&sm.bufs[0][0] + buf * 49152;
#pragma unroll
    for (int half = 0; half < 2; ++half) {
      int row = half * 32 + row8;
      int gc  = (c16s ^ (row & 7)) * 8;
      const bf16_t* ga = Ap + (size_t)(m0 + row) * sA + k0 + gc;
      char* ldst = base + (half * 32 + wv * 8) * 128;
      for (int seg = 0; seg < nseg; ++seg)
        gload16<AUX>(ga + seg * 64, ldst + seg * 8192);
    }
  };

  for (int s = 0; s < 144; ++s) {
    const bool enc = (s <= 120);
    const int  KBs = enc ? 40 : 32;
    const bf16_t* Wb0 = (enc ? WcatSw : WdecSw) + (size_t)nb0 * KBs * 512;
    const bf16_t* Wb1 = Wb0 + (size_t)KBs * 512;
    const float*  b2  = enc ? bE : bD;
    bf16_t* hw = (s < 120) ? ((s & 1) ? hP1 : hP0) : Hs + (size_t)(s - 120) * BH;
    const bf16_t* hr = (s == 0) ? nullptr
                     : (s - 1 < 120) ? (((s - 1) & 1) ? hP1 : hP0)
                                     : Hs + (size_t)(s - 1 - 120) * BH;

    f32x4 acc[4][2] = {};
    bf16x8 Bv[2][4];

    auto loadB = [&](int kb, bf16x8* B) {
      B[0] = *(const bf16x8*)(Wb0 + (size_t)kb * 512 + lane * 8);
      B[1] = *(const bf16x8*)(Wb0 + (size_t)(kb + 1) * 512 + lane * 8);
      B[2] = *(const bf16x8*)(Wb1 + (size_t)kb * 512 + lane * 8);
      B[3] = *(const bf16x8*)(Wb1 + (size_t)(kb + 1) * 512 + lane * 8);
    };
    auto compute = [&](int buf, int seg, const bf16x8* B) {
      const char* base = (const char*)&sm.bufs[0][0] + buf * 49152 + seg * 8192;
#pragma unroll
      for (int kk = 0; kk < 2; ++kk)
#pragma unroll
        for (int mi = 0; mi < 4; ++mi) {
          int row = mi * 16 + fr;
          bf16x8 av = *(const bf16x8*)(base + row * 128 +
                                       (((kk * 4 + fq) ^ (row & 7)) * 16));
          acc[mi][0] = __builtin_amdgcn_mfma_f32_16x16x32_bf16(av, B[kk],     acc[mi][0], 0, 0, 0);
          acc[mi][1] = __builtin_amdgcn_mfma_f32_16x16x32_bf16(av, B[2 + kk], acc[mi][1], 0, 0, 0);
        }
    };

    int it = 0;  // global K-iter; kb = 2*it in both layouts
    if (enc) {
      // src part: no dependency on h -> runs before the barrier wait
      int xi = (s <= 119) ? s : 119;
      const bf16_t* As = srcbf + (size_t)xi * B_SZ * DP;
      stageA(Aux<0>{}, As, DP, 0, 0, 4);
      loadB(0, Bv[0]);
      __syncthreads();
#pragma unroll
      for (int i = 0; i < 4; ++i, ++it) {
        loadB(2 * (it + 1), Bv[(it + 1) & 1]);   // it=3 prefetches h iter 0
        compute(0, i, Bv[it & 1]);
      }
    } else {
      loadB(0, Bv[0]);   // weights don't depend on h: prefetch before the spin
    }
    if (s > 0) {
      // Wait for all 32 blocks of this m-group to finish step s-1's h.
      if (t == 0) {
        while (__hip_atomic_load(&bars[(s - 1) * 8 + gI], __ATOMIC_RELAXED,
                                 __HIP_MEMORY_SCOPE_AGENT) < 32)
          __builtin_amdgcn_s_sleep(1);
      }
      __syncthreads();
      // h part: 16 iters, chunks 6(buf1) / 6(buf0) / 4(buf1); SC1 loads.
      stageA(Aux<16>{}, hr, H_SZ, 1, 0, 6);
      __syncthreads();
      stageA(Aux<16>{}, hr, H_SZ, 0, 384, 6);
#pragma unroll
      for (int i = 0; i < 6; ++i, ++it) {
        loadB(2 * (it + 1), Bv[(it + 1) & 1]);
        compute(1, i, Bv[it & 1]);
      }
      __syncthreads();
      stageA(Aux<16>{}, hr, H_SZ, 1, 768, 4);
#pragma unroll
      for (int i = 0; i < 6; ++i, ++it) {
        loadB(2 * (it + 1), Bv[(it + 1) & 1]);
        compute(0, i, Bv[it & 1]);
      }
      __syncthreads();
#pragma unroll
      for (int i = 0; i < 4; ++i, ++it) {
        if (i < 3) loadB(2 * (it + 1), Bv[(it + 1) & 1]);
        compute(1, i, Bv[it & 1]);
      }
    }

    // ---- epilogue: gates -> LDS (over buf1), cell math, write h ----
    __syncthreads();
#pragma unroll
    for (int mi = 0; mi < 4; ++mi)
#pragma unroll
      for (int nj = 0; nj < 2; ++nj)
#pragma unroll
        for (int v = 0; v < 4; ++v) {
          int row = mi * 16 + fq * 4 + v;
          int col = wv * 32 + nj * 16 + fr;
          sm.g.gate[row * 132 + col] = acc[mi][nj][v] + b2[nj];
        }
    __syncthreads();
#pragma unroll
    for (int itc = 0; itc < 8; ++itc) {
      int brw = itc * 8 + (t >> 5);
      int ju  = t & 31;
      float4 g4 = *(const float4*)(&sm.g.gate[brw * 132 + ju * 4]);
      float iv = fsigmoid(g4.x);
      float fv = fsigmoid(g4.y);
      float gv = ftanh(g4.z);
      float ov = fsigmoid(g4.w);
      float cn = fv * creg[itc] + iv * gv;
      creg[itc] = cn;
      hw[(size_t)(m0 + brw) * H_SZ + (u0 + ju)] = (bf16_t)(ov * ftanh(cn));
    }
    // syncthreads drains all waves' vmcnt (h stores in L2); the RELEASE
    // atomic then emits s_waitcnt + buffer_wbl2 (write-back, NO invalidate).
    __syncthreads();
    if (t == 0)
      __hip_atomic_fetch_add(&bars[s * 8 + gI], 1, __ATOMIC_RELEASE,
                             __HIP_MEMORY_SCOPE_AGENT);
  }
}

// ============================================================================
// One-shot GEMM kernel (Wdec build + final projection).
// ============================================================================
template <int EPI, int N1, int N2>
__global__ __launch_bounds__(256, 1) void gemm_step(
    const bf16_t* __restrict__ A1, int sA1,
    const bf16_t* __restrict__ A2, int sA2,
    const bf16_t* __restrict__ Wsw,
    const float* __restrict__ bias,
    const float* __restrict__ addm, bf16_t* __restrict__ outb,
    float* __restrict__ outf)
{
  constexpr int NTOT = N1 + N2;
  constexpr int KB   = NTOT * 2;
  constexpr int C0 = NTOT < 4 ? NTOT : 4;
  constexpr int R0 = NTOT - C0;
  constexpr int C1 = R0 < 6 ? R0 : 6;
  constexpr int R1 = R0 - C1;
  constexpr int C2 = R1 < 6 ? R1 : 6;
  constexpr int C3 = R1 - C2;
  static_assert(C3 <= 6, "chunk overflow");

  __shared__ Smem sm;
  const int t    = threadIdx.x;
  const int m0   = blockIdx.y * BM;
  const int n0   = blockIdx.x * BN;
  const int lane = t & 63;
  const int wv   = t >> 6;
  const int fr   = lane & 15;
  const int fq   = lane >> 4;

  f32x4 acc[4][2] = {};

  float bias2[2] = {0.f, 0.f};
  if (EPI == 3) {
#pragma unroll
    for (int nj = 0; nj < 2; ++nj) {
      int col = n0 + wv * 32 + nj * 16 + fr;
      bias2[nj] = (col >= D_SZ) ? 0.f : bias[col];
    }
  }

  auto stageChunk = [&](int ci, int kst, int csz) {
    const bf16_t* Ap; int sA; int kloc;
    if (ci == 0 && N1 > 0) { Ap = A1; sA = sA1; kloc = 0; }
    else                   { Ap = A2; sA = sA2; kloc = kst - N1 * BK; }
    char* base = (char*)&sm.bufs[ci & 1][0];
    const int row8 = t >> 3;
    const int c16s = (t & 7);
#pragma unroll
    for (int half = 0; half < 2; ++half) {
      int row = half * 32 + row8;
      int gc  = (c16s ^ (row & 7)) * 8;
      const bf16_t* ga = Ap + (size_t)(m0 + row) * sA + kloc + gc;
      char* ldst = base + (half * 32 + wv * 8) * 128;
      for (int seg = 0; seg < csz; ++seg)
        gload16<0>(ga + seg * 64, ldst + seg * 8192);
    }
  };

  const int nb0 = (n0 >> 4) + wv * 2;
  auto loadB = [&](int itq, bf16x8* Bv) {
#pragma unroll
    for (int nj = 0; nj < 2; ++nj)
#pragma unroll
      for (int kk = 0; kk < 2; ++kk)
        Bv[nj * 2 + kk] = *(const bf16x8*)((const char*)Wsw +
            ((size_t)((nb0 + nj) * KB + itq * 2 + kk) * 64 + lane) * 16);
  };

  auto compute = [&](const bf16x8* Bv, int bufi, int seg) {
    const char* base = (const char*)&sm.bufs[bufi][0] + seg * 8192;
#pragma unroll
    for (int kk = 0; kk < 2; ++kk)
#pragma unroll
      for (int mi = 0; mi < 4; ++mi) {
        int row = mi * 16 + fr;
        bf16x8 av = *(const bf16x8*)(base + row * 128 +
                                     (((kk * 4 + fq) ^ (row & 7)) * 16));
        acc[mi][0] = __builtin_amdgcn_mfma_f32_16x16x32_bf16(av, Bv[kk],     acc[mi][0], 0, 0, 0);
        acc[mi][1] = __builtin_amdgcn_mfma_f32_16x16x32_bf16(av, Bv[2 + kk], acc[mi][1], 0, 0, 0);
      }
  };

  bf16x8 Bv[2][4];
  loadB(0, Bv[0]);
  stageChunk(0, 0, C0);
  __syncthreads();
  if (C1 > 0) stageChunk(1, C0 * BK, C1);
#pragma unroll
  for (int i = 0; i < C0; ++i) {
    if (i + 1 < NTOT) loadB(i + 1, Bv[(i + 1) & 1]);
    compute(Bv[i & 1], 0, i);
  }
  if (C1 > 0) {
    __syncthreads();
    if (C2 > 0) stageChunk(2, (C0 + C1) * BK, C2);
#pragma unroll
    for (int i = 0; i < C1; ++i) {
      int itq = C0 + i;
      if (itq + 1 < NTOT) loadB(itq + 1, Bv[(itq + 1) & 1]);
      compute(Bv[itq & 1], 1, i);
    }
  }
  if (C2 > 0) {
    __syncthreads();
    if (C3 > 0) stageChunk(3, (C0 + C1 + C2) * BK, C3);
#pragma unroll
    for (int i = 0; i < C2; ++i) {
      int itq = C0 + C1 + i;
      if (itq + 1 < NTOT) loadB(itq + 1, Bv[(itq + 1) & 1]);
      compute(Bv[itq & 1], 0, i);
    }
  }
  if (C3 > 0) {
    __syncthreads();
#pragma unroll
    for (int i = 0; i < C3; ++i) {
      int itq = C0 + C1 + C2 + i;
      if (itq + 1 < NTOT) loadB(itq + 1, Bv[(itq + 1) & 1]);
      compute(Bv[itq & 1], 1, i);
    }
  }
  __syncthreads();

  if (EPI == 2) {
#pragma unroll
    for (int mi = 0; mi < 4; ++mi)
#pragma unroll
      for (int nj = 0; nj < 2; ++nj)
#pragma unroll
        for (int v = 0; v < 4; ++v) {
          int row = mi * 16 + fq * 4 + v;
          int col = wv * 32 + nj * 16 + fr;
          int gr = m0 + row, gc = n0 + col;
          int orig = (gr & 3) * H_SZ + (gr >> 2);
          sm.g.gate[row * 132 + col] = acc[mi][nj][v] + addm[(size_t)orig * H_SZ + gc];
        }
    __syncthreads();
#pragma unroll
    for (int q = 0; q < 4; ++q) {
      int c = q * 256 + t;
      int nbl = c >> 8, kbl = (c >> 6) & 3, l2 = c & 63;
      int nloc = nbl * 16 + (l2 & 15);
      int kloc = kbl * 32 + (l2 >> 4) * 8;
      const float* gp = &sm.g.gate[nloc * 132 + kloc];
      bf16x8 v;
#pragma unroll
      for (int j = 0; j < 8; ++j) v[j] = (bf16_t)gp[j];
      size_t chunk = (size_t)(((m0 >> 4) + nbl) * 32 + (n0 >> 5) + kbl) * 64 + l2;
      *(bf16x8*)(outb + chunk * 8) = v;
    }
  }

  if (EPI == 3) {
#pragma unroll
    for (int mi = 0; mi < 4; ++mi)
#pragma unroll
      for (int nj = 0; nj < 2; ++nj)
#pragma unroll
        for (int v = 0; v < 4; ++v) {
          int m = m0 + mi * 16 + fq * 4 + v;
          int n = n0 + wv * 32 + nj * 16 + fr;
          if (n < D_SZ) {
            outf[((size_t)(m & 511) * TMAX + (m >> 9)) * D_SZ + n] =
                acc[mi][nj][v] + bias2[nj];
          }
        }
  }
}

// src (B,S,D) fp32 -> srcbf (S,B,DP) bf16, zero-padded
__global__ void k_convert_src(const float* __restrict__ src, bf16_t* __restrict__ dst) {
  int idx = blockIdx.x * 256 + threadIdx.x;
  int total = S_SZ * B_SZ * DP;
  if (idx >= total) return;
  int d = idx % DP;
  int r = idx / DP;
  int b = r % B_SZ;
  int tt = r / B_SZ;
  float v = (d < D_SZ) ? src[((size_t)b * S_SZ + tt) * D_SZ + d] : 0.f;
  dst[idx] = (bf16_t)v;
}

// Swizzled W_cat (N=4096 gate-interleaved rows, K=1280: [Wih|0|Whh]), KB=40
__global__ void k_build_wcat_sw(const float* __restrict__ Wih, const float* __restrict__ Whh,
                                bf16_t* __restrict__ out) {
  int c = blockIdx.x * 256 + threadIdx.x;
  if (c >= 256 * 40 * 64) return;
  int l = c & 63;
  int kb = (c >> 6) % 40;
  int nb = c / (40 * 64);
  int n = nb * 16 + (l & 15);
  int k0 = kb * 32 + (l >> 4) * 8;
  int o = (n & 3) * H_SZ + (n >> 2);
  bf16x8 v;
#pragma unroll
  for (int j = 0; j < 8; ++j) {
    int k = k0 + j;
    float x = (k < D_SZ) ? Wih[(size_t)o * D_SZ + k]
            : (k < DP ? 0.f : Whh[(size_t)o * H_SZ + (k - DP)]);
    v[j] = (bf16_t)x;
  }
  *(bf16x8*)(out + (size_t)c * 8) = v;
}

// Swizzled B for Wdec build: B[n=h][k=d] = Wout[d][h], KB=8
__global__ void k_build_woutt_sw(const float* __restrict__ Wout, bf16_t* __restrict__ out) {
  int c = blockIdx.x * 256 + threadIdx.x;
  if (c >= 64 * 8 * 64) return;
  int l = c & 63;
  int kb = (c >> 6) % 8;
  int nb = c / (8 * 64);
  int n = nb * 16 + (l & 15);
  int k0 = kb * 32 + (l >> 4) * 8;
  bf16x8 v;
#pragma unroll
  for (int j = 0; j < 8; ++j) {
    int k = k0 + j;
    v[j] = (bf16_t)((k < D_SZ) ? Wout[(size_t)k * H_SZ + n] : 0.f);
  }
  *(bf16x8*)(out + (size_t)c * 8) = v;
}

// Swizzled B for final projection: B[n=d][k=h] = Wout[d][h], KB=32
__global__ void k_build_wout_sw(const float* __restrict__ Wout, bf16_t* __restrict__ out) {
  int c = blockIdx.x * 256 + threadIdx.x;
  if (c >= 16 * 32 * 64) return;
  int l = c & 63;
  int kb = (c >> 6) % 32;
  int nb = c / (32 * 64);
  int n = nb * 16 + (l & 15);
  int k0 = kb * 32 + (l >> 4) * 8;
  bf16x8 v;
#pragma unroll
  for (int j = 0; j < 8; ++j)
    v[j] = (bf16_t)((n < D_SZ) ? Wout[(size_t)n * H_SZ + k0 + j] : 0.f);
  *(bf16x8*)(out + (size_t)c * 8) = v;
}

// Natural A for Wdec build: [4096 gate rows][256 d-pad] bf16
__global__ void k_build_wihre(const float* __restrict__ Wih, bf16_t* __restrict__ out) {
  int c = blockIdx.x * 256 + threadIdx.x;
  if (c >= 4096 * 32) return;
  int r = c >> 5;
  int k0 = (c & 31) * 8;
  int o = (r & 3) * H_SZ + (r >> 2);
  bf16x8 v;
#pragma unroll
  for (int j = 0; j < 8; ++j) {
    int k = k0 + j;
    v[j] = (bf16_t)((k < D_SZ) ? Wih[(size_t)o * D_SZ + k] : 0.f);
  }
  *(bf16x8*)(out + (size_t)c * 8) = v;
}

// bias_enc[r] = b_ih[o]+b_hh[o];  bias_dec[r] = bias_enc[r] + W_ih[o,:].b_out
__global__ void k_build_bias(const float* __restrict__ bih, const float* __restrict__ bhh,
                             const float* __restrict__ Wih, const float* __restrict__ bout,
                             float* __restrict__ biasE, float* __restrict__ biasD) {
  int r = blockIdx.x * 256 + threadIdx.x;
  if (r >= NG) return;
  int o = (r & 3) * H_SZ + (r >> 2);
  float be = bih[o] + bhh[o];
  biasE[r] = be;
  float s = 0.f;
  const float* wr = Wih + (size_t)o * D_SZ;
  for (int d = 0; d < D_SZ; ++d) s += wr[d] * bout[d];
  biasD[r] = be + s;
}

extern "C" void kernel_launch(void* const* d_in, const int* in_sizes, int n_in,
                              void* d_out, int out_size, void* d_ws, size_t ws_size,
                              hipStream_t stream) {
  const float* src  = (const float*)d_in[0];
  const float* Wih  = (const float*)d_in[1];
  const float* Whh  = (const float*)d_in[2];
  const float* bih  = (const float*)d_in[3];
  const float* bhh  = (const float*)d_in[4];
  const float* Wout = (const float*)d_in[5];
  const float* bout = (const float*)d_in[6];

  char* ws = (char*)d_ws;
  size_t off = 0;
  auto alloc = [&](size_t bytes) {
    void* p = ws + off;
    off = (off + bytes + 255) & ~(size_t)255;
    return p;
  };
  bf16_t* srcbf  = (bf16_t*)alloc((size_t)S_SZ * B_SZ * DP * 2);   // 31.5 MB
  bf16_t* WcatSw = (bf16_t*)alloc((size_t)256 * 40 * 64 * 16);     // 10.5 MB
  bf16_t* WdecSw = (bf16_t*)alloc((size_t)NG * H_SZ * 2);          //  8.4 MB
  bf16_t* WouttSw= (bf16_t*)alloc((size_t)64 * 8 * 64 * 16);
  bf16_t* WoutSw = (bf16_t*)alloc((size_t)16 * 32 * 64 * 16);
  bf16_t* WihRe  = (bf16_t*)alloc((size_t)NG * DP * 2);            //  2 MB
  float*  biasE  = (float*)alloc((size_t)NG * 4);
  float*  biasD  = (float*)alloc((size_t)NG * 4);
  bf16_t* hP0    = (bf16_t*)alloc((size_t)B_SZ * H_SZ * 2);
  bf16_t* hP1    = (bf16_t*)alloc((size_t)B_SZ * H_SZ * 2);
  bf16_t* Hs     = (bf16_t*)alloc((size_t)TMAX * B_SZ * H_SZ * 2); // 25.2 MB
  int*    bars   = (int*)alloc((size_t)144 * 8 * 4);

  hipMemsetAsync(bars, 0, (size_t)144 * 8 * 4, stream);

  k_convert_src<<<(S_SZ * B_SZ * DP + 255) / 256, 256, 0, stream>>>(src, srcbf);
  k_build_wcat_sw<<<(256 * 40 * 64 + 255) / 256, 256, 0, stream>>>(Wih, Whh, WcatSw);
  k_build_woutt_sw<<<(64 * 8 * 64 + 255) / 256, 256, 0, stream>>>(Wout, WouttSw);
  k_build_wout_sw<<<(16 * 32 * 64 + 255) / 256, 256, 0, stream>>>(Wout, WoutSw);
  k_build_wihre<<<(4096 * 32 + 255) / 256, 256, 0, stream>>>(Wih, WihRe);
  k_build_bias<<<(NG + 255) / 256, 256, 0, stream>>>(bih, bhh, Wih, bout, biasE, biasD);

  // W_dec(swizzled) = Whh_reord + Wih_reord @ Wout  (M=4096, N=1024, K=256)
  gemm_step<2, 4, 0><<<dim3(H_SZ / BN, NG / BM), 256, 0, stream>>>(
      WihRe, DP, nullptr, 0, WouttSw, nullptr, Whh, WdecSw, nullptr);

  // All 144 recurrent steps in one persistent kernel.
  lstm_persist<<<dim3(32, 8), 256, 0, stream>>>(
      srcbf, WcatSw, WdecSw, biasE, biasD, hP0, hP1, Hs, bars);

  // Final projection: Y(12288 x 216) = Hs(12288 x 1024) @ Wout^T + b_out
  gemm_step<3, 0, 16><<<dim3(2, (TMAX * B_SZ) / BM), 256, 0, stream>>>(
      nullptr, 0, Hs, H_SZ, WoutSw, bout, nullptr, nullptr, (float*)d_out);
}

// Round 7
// 2533.703 us; speedup vs baseline: 2.8842x; 1.0972x over previous
//
#include <hip/hip_runtime.h>
#include <cstdint>
#include <cstddef>

// Problem constants
#define B_SZ 512
#define S_SZ 120
#define D_SZ 216
#define H_SZ 1024
#define NG   4096     // 4*H
#define DP   256      // D padded
#define TMAX 24

// GEMM tile config: block 64(M) x 128(N), BK=64, 4 waves 1x4 (wave = 64M x 32N)
#define BM 64
#define BN 128
#define BK 64

using bf16_t = __bf16;
using bf16x8 = __attribute__((ext_vector_type(8))) __bf16;
using f32x4  = __attribute__((ext_vector_type(4))) float;

__device__ __forceinline__ void gload16(const void* g, void* l) {
  __builtin_amdgcn_global_load_lds(
      (const __attribute__((address_space(1))) void*)g,
      (__attribute__((address_space(3))) void*)l, 16, 0, 0);
}

__device__ __forceinline__ float fsigmoid(float x) {
  x = fminf(fmaxf(x, -30.f), 30.f);
  return 1.f / (1.f + __expf(-x));
}
__device__ __forceinline__ float ftanh(float x) {
  x = fminf(fmaxf(x, -15.f), 15.f);
  float e = __expf(2.f * x);
  return (e - 1.f) / (e + 1.f);
}

// LDS: two A-staging buffers (6 segs x 64 rows x 128 B = 48 KB each).
// A stored [seg][row][128B] with XOR 16B-chunk swizzle on the GLOBAL side:
// LDS slot (row, c) holds global chunk c ^ (row&7). gate[] unions over buf1.
// gate stride 132 floats (16B-aligned rows -> float4 reads = ds_read_b128,
// 2-way bank aliasing = free; r6 measured SQ_LDS_BANK_CONFLICT = 0).
struct __align__(16) Smem {
  union {
    bf16_t bufs[2][6 * 64 * 64];                      // 2 x 49152 B
    struct { char pad[49152]; float gate[64 * 132]; } g;
  };
};

// Weight swizzled layout ("fragment-major"): for frag (nb = n>>4, kb = k>>5):
// chunk lane l = ((k>>3)&3)*16 + (n&15), 8 k-contiguous bf16 per lane.
// flat 16B-chunk id = (nb*KB + kb)*64 + l, KB = K/32.

// ============================================================================
// Persistent kernel: all 144 LSTM steps in one launch.
// Grid dim3(32, 8): x = n-tile (128 gate cols), y = m-group (64 batch rows).
// Block (x,y) at step s needs h rows y*64..+63 (all cols) = outputs of the 32
// blocks sharing y.
// Coherence design (r5/r6 lessons): h is WRITE-ONCE -- one buffer per step
// (Hsteps[s]) -- so no L1/L2 can ever hold a stale copy of an h address;
// plain cached loads are then legal (full per-XCD L2 reuse, 4 blocks share
// each 128 KB slice). Producer: __syncthreads (drains vmcnt) + t0 RELEASE
// agent atomic (buffer_wbl2: write-back only, weights stay L2-resident --
// r5's __threadfence() emitted buffer_inv -> 718 MB HBM refetch; r6's SC1
// loads bypassed consumer L2 -> 4x fabric amplification).
// All 256 blocks co-resident (1 block/CU via 96KB LDS + launch_bounds).
// ============================================================================
__global__ __launch_bounds__(256, 1) void lstm_persist(
    const bf16_t* __restrict__ srcbf,   // (S, B, DP) bf16
    const bf16_t* __restrict__ WcatSw,  // swizzled, KB=40 (src kb 0..7, h kb 8..39)
    const bf16_t* __restrict__ WdecSw,  // swizzled, KB=32
    const float* __restrict__ biasE,
    const float* __restrict__ biasD,
    bf16_t* __restrict__ Hsteps,        // (144, B, H) per-step h (write-once)
    int* __restrict__ bars)             // [144][8] arrival counters (zeroed)
{
  __shared__ Smem sm;
  const int t    = threadIdx.x;
  const int nt   = blockIdx.x;       // n-tile 0..31
  const int gI   = blockIdx.y;       // m-group 0..7
  const int m0   = gI * BM;
  const int n0   = nt * BN;
  const int lane = t & 63;
  const int wv   = t >> 6;
  const int fr   = lane & 15;
  const int fq   = lane >> 4;
  const int u0   = n0 >> 2;
  const size_t BH = (size_t)B_SZ * H_SZ;

  // Bias registers (both variants)
  float bE[2], bD[2];
#pragma unroll
  for (int nj = 0; nj < 2; ++nj) {
    int col = n0 + wv * 32 + nj * 16 + fr;
    bE[nj] = biasE[col];
    bD[nj] = biasD[col];
  }

  // Cell state in registers: thread t owns (row = itc*8 + (t>>5), unit u0+(t&31))
  float creg[8];
#pragma unroll
  for (int i = 0; i < 8; ++i) creg[i] = 0.f;

  const int nb0  = (n0 >> 4) + wv * 2;
  const int row8 = t >> 3;
  const int c16s = t & 7;

  // A staging with XOR swizzle; LDS dest is wave-uniform base + lane*16.
  auto stageA = [&](const bf16_t* Ap, int sA, int buf, int k0, int nseg) {
    char* base = (char*)&sm.bufs[0][0] + buf * 49152;
#pragma unroll
    for (int half = 0; half < 2; ++half) {
      int row = half * 32 + row8;
      int gc  = (c16s ^ (row & 7)) * 8;
      const bf16_t* ga = Ap + (size_t)(m0 + row) * sA + k0 + gc;
      char* ldst = base + (half * 32 + wv * 8) * 128;
      for (int seg = 0; seg < nseg; ++seg)
        gload16(ga + seg * 64, ldst + seg * 8192);
    }
  };

  for (int s = 0; s < 144; ++s) {
    const bool enc = (s <= 120);
    const int  KBs = enc ? 40 : 32;
    const bf16_t* Wb0 = (enc ? WcatSw : WdecSw) + (size_t)nb0 * KBs * 512;
    const bf16_t* Wb1 = Wb0 + (size_t)KBs * 512;
    const float*  b2  = enc ? bE : bD;
    bf16_t* hw = Hsteps + (size_t)s * BH;            // write-once per step
    const bf16_t* hr = Hsteps + (size_t)(s - 1) * BH;

    f32x4 acc[4][2] = {};
    bf16x8 Bv[2][4];

    auto loadB = [&](int kb, bf16x8* B) {
      B[0] = *(const bf16x8*)(Wb0 + (size_t)kb * 512 + lane * 8);
      B[1] = *(const bf16x8*)(Wb0 + (size_t)(kb + 1) * 512 + lane * 8);
      B[2] = *(const bf16x8*)(Wb1 + (size_t)kb * 512 + lane * 8);
      B[3] = *(const bf16x8*)(Wb1 + (size_t)(kb + 1) * 512 + lane * 8);
    };
    auto compute = [&](int buf, int seg, const bf16x8* B) {
      const char* base = (const char*)&sm.bufs[0][0] + buf * 49152 + seg * 8192;
#pragma unroll
      for (int kk = 0; kk < 2; ++kk)
#pragma unroll
        for (int mi = 0; mi < 4; ++mi) {
          int row = mi * 16 + fr;
          bf16x8 av = *(const bf16x8*)(base + row * 128 +
                                       (((kk * 4 + fq) ^ (row & 7)) * 16));
          acc[mi][0] = __builtin_amdgcn_mfma_f32_16x16x32_bf16(av, B[kk],     acc[mi][0], 0, 0, 0);
          acc[mi][1] = __builtin_amdgcn_mfma_f32_16x16x32_bf16(av, B[2 + kk], acc[mi][1], 0, 0, 0);
        }
    };

    int it = 0;  // global K-iter; kb = 2*it in both layouts
    if (enc) {
      // src part: no dependency on h -> runs before the barrier wait
      int xi = (s <= 119) ? s : 119;
      const bf16_t* As = srcbf + (size_t)xi * B_SZ * DP;
      stageA(As, DP, 0, 0, 4);
      loadB(0, Bv[0]);
      __syncthreads();
#pragma unroll
      for (int i = 0; i < 4; ++i, ++it) {
        loadB(2 * (it + 1), Bv[(it + 1) & 1]);   // it=3 prefetches h iter 0
        compute(0, i, Bv[it & 1]);
      }
    } else {
      loadB(0, Bv[0]);   // weights don't depend on h: prefetch before the spin
    }
    if (s > 0) {
      // Wait for all 32 blocks of this m-group to finish step s-1's h.
      if (t == 0) {
        while (__hip_atomic_load(&bars[(s - 1) * 8 + gI], __ATOMIC_RELAXED,
                                 __HIP_MEMORY_SCOPE_AGENT) < 32)
          __builtin_amdgcn_s_sleep(1);
      }
      __syncthreads();
      // h part: 16 iters, chunks 6(buf1) / 6(buf0) / 4(buf1); plain cached
      // loads (write-once buffer -> no stale-line hazard, full L2 reuse).
      stageA(hr, H_SZ, 1, 0, 6);
      __syncthreads();
      stageA(hr, H_SZ, 0, 384, 6);
#pragma unroll
      for (int i = 0; i < 6; ++i, ++it) {
        loadB(2 * (it + 1), Bv[(it + 1) & 1]);
        compute(1, i, Bv[it & 1]);
      }
      __syncthreads();
      stageA(hr, H_SZ, 1, 768, 4);
#pragma unroll
      for (int i = 0; i < 6; ++i, ++it) {
        loadB(2 * (it + 1), Bv[(it + 1) & 1]);
        compute(0, i, Bv[it & 1]);
      }
      __syncthreads();
#pragma unroll
      for (int i = 0; i < 4; ++i, ++it) {
        if (i < 3) loadB(2 * (it + 1), Bv[(it + 1) & 1]);
        compute(1, i, Bv[it & 1]);
      }
    }

    // ---- epilogue: gates -> LDS (over buf1), cell math, write h ----
    __syncthreads();
#pragma unroll
    for (int mi = 0; mi < 4; ++mi)
#pragma unroll
      for (int nj = 0; nj < 2; ++nj)
#pragma unroll
        for (int v = 0; v < 4; ++v) {
          int row = mi * 16 + fq * 4 + v;
          int col = wv * 32 + nj * 16 + fr;
          sm.g.gate[row * 132 + col] = acc[mi][nj][v] + b2[nj];
        }
    __syncthreads();
#pragma unroll
    for (int itc = 0; itc < 8; ++itc) {
      int brw = itc * 8 + (t >> 5);
      int ju  = t & 31;
      float4 g4 = *(const float4*)(&sm.g.gate[brw * 132 + ju * 4]);
      float iv = fsigmoid(g4.x);
      float fv = fsigmoid(g4.y);
      float gv = ftanh(g4.z);
      float ov = fsigmoid(g4.w);
      float cn = fv * creg[itc] + iv * gv;
      creg[itc] = cn;
      hw[(size_t)(m0 + brw) * H_SZ + (u0 + ju)] = (bf16_t)(ov * ftanh(cn));
    }
    // syncthreads drains all waves' vmcnt (h stores in L2); the RELEASE
    // atomic then emits s_waitcnt + buffer_wbl2 (write-back, NO invalidate).
    __syncthreads();
    if (t == 0)
      __hip_atomic_fetch_add(&bars[s * 8 + gI], 1, __ATOMIC_RELEASE,
                             __HIP_MEMORY_SCOPE_AGENT);
  }
}

// ============================================================================
// One-shot GEMM kernel (Wdec build + final projection).
// ============================================================================
template <int EPI, int N1, int N2>
__global__ __launch_bounds__(256, 1) void gemm_step(
    const bf16_t* __restrict__ A1, int sA1,
    const bf16_t* __restrict__ A2, int sA2,
    const bf16_t* __restrict__ Wsw,
    const float* __restrict__ bias,
    const float* __restrict__ addm, bf16_t* __restrict__ outb,
    float* __restrict__ outf)
{
  constexpr int NTOT = N1 + N2;
  constexpr int KB   = NTOT * 2;
  constexpr int C0 = NTOT < 4 ? NTOT : 4;
  constexpr int R0 = NTOT - C0;
  constexpr int C1 = R0 < 6 ? R0 : 6;
  constexpr int R1 = R0 - C1;
  constexpr int C2 = R1 < 6 ? R1 : 6;
  constexpr int C3 = R1 - C2;
  static_assert(C3 <= 6, "chunk overflow");

  __shared__ Smem sm;
  const int t    = threadIdx.x;
  const int m0   = blockIdx.y * BM;
  const int n0   = blockIdx.x * BN;
  const int lane = t & 63;
  const int wv   = t >> 6;
  const int fr   = lane & 15;
  const int fq   = lane >> 4;

  f32x4 acc[4][2] = {};

  float bias2[2] = {0.f, 0.f};
  if (EPI == 3) {
#pragma unroll
    for (int nj = 0; nj < 2; ++nj) {
      int col = n0 + wv * 32 + nj * 16 + fr;
      bias2[nj] = (col >= D_SZ) ? 0.f : bias[col];
    }
  }

  auto stageChunk = [&](int ci, int kst, int csz) {
    const bf16_t* Ap; int sA; int kloc;
    if (ci == 0 && N1 > 0) { Ap = A1; sA = sA1; kloc = 0; }
    else                   { Ap = A2; sA = sA2; kloc = kst - N1 * BK; }
    char* base = (char*)&sm.bufs[ci & 1][0];
    const int row8 = t >> 3;
    const int c16s = (t & 7);
#pragma unroll
    for (int half = 0; half < 2; ++half) {
      int row = half * 32 + row8;
      int gc  = (c16s ^ (row & 7)) * 8;
      const bf16_t* ga = Ap + (size_t)(m0 + row) * sA + kloc + gc;
      char* ldst = base + (half * 32 + wv * 8) * 128;
      for (int seg = 0; seg < csz; ++seg)
        gload16(ga + seg * 64, ldst + seg * 8192);
    }
  };

  const int nb0 = (n0 >> 4) + wv * 2;
  auto loadB = [&](int itq, bf16x8* Bv) {
#pragma unroll
    for (int nj = 0; nj < 2; ++nj)
#pragma unroll
      for (int kk = 0; kk < 2; ++kk)
        Bv[nj * 2 + kk] = *(const bf16x8*)((const char*)Wsw +
            ((size_t)((nb0 + nj) * KB + itq * 2 + kk) * 64 + lane) * 16);
  };

  auto compute = [&](const bf16x8* Bv, int bufi, int seg) {
    const char* base = (const char*)&sm.bufs[bufi][0] + seg * 8192;
#pragma unroll
    for (int kk = 0; kk < 2; ++kk)
#pragma unroll
      for (int mi = 0; mi < 4; ++mi) {
        int row = mi * 16 + fr;
        bf16x8 av = *(const bf16x8*)(base + row * 128 +
                                     (((kk * 4 + fq) ^ (row & 7)) * 16));
        acc[mi][0] = __builtin_amdgcn_mfma_f32_16x16x32_bf16(av, Bv[kk],     acc[mi][0], 0, 0, 0);
        acc[mi][1] = __builtin_amdgcn_mfma_f32_16x16x32_bf16(av, Bv[2 + kk], acc[mi][1], 0, 0, 0);
      }
  };

  bf16x8 Bv[2][4];
  loadB(0, Bv[0]);
  stageChunk(0, 0, C0);
  __syncthreads();
  if (C1 > 0) stageChunk(1, C0 * BK, C1);
#pragma unroll
  for (int i = 0; i < C0; ++i) {
    if (i + 1 < NTOT) loadB(i + 1, Bv[(i + 1) & 1]);
    compute(Bv[i & 1], 0, i);
  }
  if (C1 > 0) {
    __syncthreads();
    if (C2 > 0) stageChunk(2, (C0 + C1) * BK, C2);
#pragma unroll
    for (int i = 0; i < C1; ++i) {
      int itq = C0 + i;
      if (itq + 1 < NTOT) loadB(itq + 1, Bv[(itq + 1) & 1]);
      compute(Bv[itq & 1], 1, i);
    }
  }
  if (C2 > 0) {
    __syncthreads();
    if (C3 > 0) stageChunk(3, (C0 + C1 + C2) * BK, C3);
#pragma unroll
    for (int i = 0; i < C2; ++i) {
      int itq = C0 + C1 + i;
      if (itq + 1 < NTOT) loadB(itq + 1, Bv[(itq + 1) & 1]);
      compute(Bv[itq & 1], 0, i);
    }
  }
  if (C3 > 0) {
    __syncthreads();
#pragma unroll
    for (int i = 0; i < C3; ++i) {
      int itq = C0 + C1 + C2 + i;
      if (itq + 1 < NTOT) loadB(itq + 1, Bv[(itq + 1) & 1]);
      compute(Bv[itq & 1], 1, i);
    }
  }
  __syncthreads();

  if (EPI == 2) {
#pragma unroll
    for (int mi = 0; mi < 4; ++mi)
#pragma unroll
      for (int nj = 0; nj < 2; ++nj)
#pragma unroll
        for (int v = 0; v < 4; ++v) {
          int row = mi * 16 + fq * 4 + v;
          int col = wv * 32 + nj * 16 + fr;
          int gr = m0 + row, gc = n0 + col;
          int orig = (gr & 3) * H_SZ + (gr >> 2);
          sm.g.gate[row * 132 + col] = acc[mi][nj][v] + addm[(size_t)orig * H_SZ + gc];
        }
    __syncthreads();
#pragma unroll
    for (int q = 0; q < 4; ++q) {
      int c = q * 256 + t;
      int nbl = c >> 8, kbl = (c >> 6) & 3, l2 = c & 63;
      int nloc = nbl * 16 + (l2 & 15);
      int kloc = kbl * 32 + (l2 >> 4) * 8;
      const float* gp = &sm.g.gate[nloc * 132 + kloc];
      bf16x8 v;
#pragma unroll
      for (int j = 0; j < 8; ++j) v[j] = (bf16_t)gp[j];
      size_t chunk = (size_t)(((m0 >> 4) + nbl) * 32 + (n0 >> 5) + kbl) * 64 + l2;
      *(bf16x8*)(outb + chunk * 8) = v;
    }
  }

  if (EPI == 3) {
#pragma unroll
    for (int mi = 0; mi < 4; ++mi)
#pragma unroll
      for (int nj = 0; nj < 2; ++nj)
#pragma unroll
        for (int v = 0; v < 4; ++v) {
          int m = m0 + mi * 16 + fq * 4 + v;
          int n = n0 + wv * 32 + nj * 16 + fr;
          if (n < D_SZ) {
            outf[((size_t)(m & 511) * TMAX + (m >> 9)) * D_SZ + n] =
                acc[mi][nj][v] + bias2[nj];
          }
        }
  }
}

// src (B,S,D) fp32 -> srcbf (S,B,DP) bf16, zero-padded
__global__ void k_convert_src(const float* __restrict__ src, bf16_t* __restrict__ dst) {
  int idx = blockIdx.x * 256 + threadIdx.x;
  int total = S_SZ * B_SZ * DP;
  if (idx >= total) return;
  int d = idx % DP;
  int r = idx / DP;
  int b = r % B_SZ;
  int tt = r / B_SZ;
  float v = (d < D_SZ) ? src[((size_t)b * S_SZ + tt) * D_SZ + d] : 0.f;
  dst[idx] = (bf16_t)v;
}

// Swizzled W_cat (N=4096 gate-interleaved rows, K=1280: [Wih|0|Whh]), KB=40
__global__ void k_build_wcat_sw(const float* __restrict__ Wih, const float* __restrict__ Whh,
                                bf16_t* __restrict__ out) {
  int c = blockIdx.x * 256 + threadIdx.x;
  if (c >= 256 * 40 * 64) return;
  int l = c & 63;
  int kb = (c >> 6) % 40;
  int nb = c / (40 * 64);
  int n = nb * 16 + (l & 15);
  int k0 = kb * 32 + (l >> 4) * 8;
  int o = (n & 3) * H_SZ + (n >> 2);
  bf16x8 v;
#pragma unroll
  for (int j = 0; j < 8; ++j) {
    int k = k0 + j;
    float x = (k < D_SZ) ? Wih[(size_t)o * D_SZ + k]
            : (k < DP ? 0.f : Whh[(size_t)o * H_SZ + (k - DP)]);
    v[j] = (bf16_t)x;
  }
  *(bf16x8*)(out + (size_t)c * 8) = v;
}

// Swizzled B for Wdec build: B[n=h][k=d] = Wout[d][h], KB=8
__global__ void k_build_woutt_sw(const float* __restrict__ Wout, bf16_t* __restrict__ out) {
  int c = blockIdx.x * 256 + threadIdx.x;
  if (c >= 64 * 8 * 64) return;
  int l = c & 63;
  int kb = (c >> 6) % 8;
  int nb = c / (8 * 64);
  int n = nb * 16 + (l & 15);
  int k0 = kb * 32 + (l >> 4) * 8;
  bf16x8 v;
#pragma unroll
  for (int j = 0; j < 8; ++j) {
    int k = k0 + j;
    v[j] = (bf16_t)((k < D_SZ) ? Wout[(size_t)k * H_SZ + n] : 0.f);
  }
  *(bf16x8*)(out + (size_t)c * 8) = v;
}

// Swizzled B for final projection: B[n=d][k=h] = Wout[d][h], KB=32
__global__ void k_build_wout_sw(const float* __restrict__ Wout, bf16_t* __restrict__ out) {
  int c = blockIdx.x * 256 + threadIdx.x;
  if (c >= 16 * 32 * 64) return;
  int l = c & 63;
  int kb = (c >> 6) % 32;
  int nb = c / (32 * 64);
  int n = nb * 16 + (l & 15);
  int k0 = kb * 32 + (l >> 4) * 8;
  bf16x8 v;
#pragma unroll
  for (int j = 0; j < 8; ++j)
    v[j] = (bf16_t)((n < D_SZ) ? Wout[(size_t)n * H_SZ + k0 + j] : 0.f);
  *(bf16x8*)(out + (size_t)c * 8) = v;
}

// Natural A for Wdec build: [4096 gate rows][256 d-pad] bf16
__global__ void k_build_wihre(const float* __restrict__ Wih, bf16_t* __restrict__ out) {
  int c = blockIdx.x * 256 + threadIdx.x;
  if (c >= 4096 * 32) return;
  int r = c >> 5;
  int k0 = (c & 31) * 8;
  int o = (r & 3) * H_SZ + (r >> 2);
  bf16x8 v;
#pragma unroll
  for (int j = 0; j < 8; ++j) {
    int k = k0 + j;
    v[j] = (bf16_t)((k < D_SZ) ? Wih[(size_t)o * D_SZ + k] : 0.f);
  }
  *(bf16x8*)(out + (size_t)c * 8) = v;
}

// bias_enc[r] = b_ih[o]+b_hh[o];  bias_dec[r] = bias_enc[r] + W_ih[o,:].b_out
__global__ void k_build_bias(const float* __restrict__ bih, const float* __restrict__ bhh,
                             const float* __restrict__ Wih, const float* __restrict__ bout,
                             float* __restrict__ biasE, float* __restrict__ biasD) {
  int r = blockIdx.x * 256 + threadIdx.x;
  if (r >= NG) return;
  int o = (r & 3) * H_SZ + (r >> 2);
  float be = bih[o] + bhh[o];
  biasE[r] = be;
  float s = 0.f;
  const float* wr = Wih + (size_t)o * D_SZ;
  for (int d = 0; d < D_SZ; ++d) s += wr[d] * bout[d];
  biasD[r] = be + s;
}

extern "C" void kernel_launch(void* const* d_in, const int* in_sizes, int n_in,
                              void* d_out, int out_size, void* d_ws, size_t ws_size,
                              hipStream_t stream) {
  const float* src  = (const float*)d_in[0];
  const float* Wih  = (const float*)d_in[1];
  const float* Whh  = (const float*)d_in[2];
  const float* bih  = (const float*)d_in[3];
  const float* bhh  = (const float*)d_in[4];
  const float* Wout = (const float*)d_in[5];
  const float* bout = (const float*)d_in[6];

  char* ws = (char*)d_ws;
  size_t off = 0;
  auto alloc = [&](size_t bytes) {
    void* p = ws + off;
    off = (off + bytes + 255) & ~(size_t)255;
    return p;
  };
  bf16_t* srcbf  = (bf16_t*)alloc((size_t)S_SZ * B_SZ * DP * 2);   // 31.5 MB
  bf16_t* WcatSw = (bf16_t*)alloc((size_t)256 * 40 * 64 * 16);     // 10.5 MB
  bf16_t* WdecSw = (bf16_t*)alloc((size_t)NG * H_SZ * 2);          //  8.4 MB
  bf16_t* WouttSw= (bf16_t*)alloc((size_t)64 * 8 * 64 * 16);
  bf16_t* WoutSw = (bf16_t*)alloc((size_t)16 * 32 * 64 * 16);
  bf16_t* WihRe  = (bf16_t*)alloc((size_t)NG * DP * 2);            //  2 MB
  float*  biasE  = (float*)alloc((size_t)NG * 4);
  float*  biasD  = (float*)alloc((size_t)NG * 4);
  bf16_t* Hsteps = (bf16_t*)alloc((size_t)144 * B_SZ * H_SZ * 2);  // 151 MB
  int*    bars   = (int*)alloc((size_t)144 * 8 * 4);

  hipMemsetAsync(bars, 0, (size_t)144 * 8 * 4, stream);

  k_convert_src<<<(S_SZ * B_SZ * DP + 255) / 256, 256, 0, stream>>>(src, srcbf);
  k_build_wcat_sw<<<(256 * 40 * 64 + 255) / 256, 256, 0, stream>>>(Wih, Whh, WcatSw);
  k_build_woutt_sw<<<(64 * 8 * 64 + 255) / 256, 256, 0, stream>>>(Wout, WouttSw);
  k_build_wout_sw<<<(16 * 32 * 64 + 255) / 256, 256, 0, stream>>>(Wout, WoutSw);
  k_build_wihre<<<(4096 * 32 + 255) / 256, 256, 0, stream>>>(Wih, WihRe);
  k_build_bias<<<(NG + 255) / 256, 256, 0, stream>>>(bih, bhh, Wih, bout, biasE, biasD);

  // W_dec(swizzled) = Whh_reord + Wih_reord @ Wout  (M=4096, N=1024, K=256)
  gemm_step<2, 4, 0><<<dim3(H_SZ / BN, NG / BM), 256, 0, stream>>>(
      WihRe, DP, nullptr, 0, WouttSw, nullptr, Whh, WdecSw, nullptr);

  // All 144 recurrent steps in one persistent kernel.
  lstm_persist<<<dim3(32, 8), 256, 0, stream>>>(
      srcbf, WcatSw, WdecSw, biasE, biasD, Hsteps, bars);

  // Final projection: Y(12288 x 216) = Hs(12288 x 1024) @ Wout^T + b_out
  // (decoder h = Hsteps slots 120..143, contiguous)
  gemm_step<3, 0, 16><<<dim3(2, (TMAX * B_SZ) / BM), 256, 0, stream>>>(
      nullptr, 0, Hsteps + (size_t)120 * B_SZ * H_SZ, H_SZ, WoutSw, bout,
      nullptr, nullptr, (float*)d_out);
}

// Round 8
// 2073.844 us; speedup vs baseline: 3.5237x; 1.2217x over previous
//
#include <hip/hip_runtime.h>
#include <cstdint>
#include <cstddef>

// Problem constants
#define B_SZ 512
#define S_SZ 120
#define D_SZ 216
#define H_SZ 1024
#define NG   4096     // 4*H
#define DP   256      // D padded
#define TMAX 24

// GEMM tile config: block 64(M) x 128(N), BK=64, 4 waves 1x4 (wave = 64M x 32N)
#define BM 64
#define BN 128
#define BK 64

using bf16_t = __bf16;
using bf16x8 = __attribute__((ext_vector_type(8))) __bf16;
using f32x4  = __attribute__((ext_vector_type(4))) float;

__device__ __forceinline__ void gload16(const void* g, void* l) {
  __builtin_amdgcn_global_load_lds(
      (const __attribute__((address_space(1))) void*)g,
      (__attribute__((address_space(3))) void*)l, 16, 0, 0);
}

__device__ __forceinline__ float fsigmoid(float x) {
  x = fminf(fmaxf(x, -30.f), 30.f);
  return 1.f / (1.f + __expf(-x));
}
__device__ __forceinline__ float ftanh(float x) {
  x = fminf(fmaxf(x, -15.f), 15.f);
  float e = __expf(2.f * x);
  return (e - 1.f) / (e + 1.f);
}

// LDS: two A-staging buffers (6 segs x 64 rows x 128 B = 48 KB each).
// A stored [seg][row][128B] with XOR 16B-chunk swizzle on the GLOBAL side:
// LDS slot (row, c) holds global chunk c ^ (row&7). gate[] unions over buf1.
// gate stride 132 floats (16B-aligned rows -> float4 reads = ds_read_b128,
// 2-way bank aliasing = free; measured SQ_LDS_BANK_CONFLICT = 0).
struct __align__(16) Smem {
  union {
    bf16_t bufs[2][6 * 64 * 64];                      // 2 x 49152 B
    struct { char pad[49152]; float gate[64 * 132]; } g;
  };
};

// Weight swizzled layout ("fragment-major"): for frag (nb = n>>4, kb = k>>5):
// chunk lane l = ((k>>3)&3)*16 + (n&15), 8 k-contiguous bf16 per lane.
// flat 16B-chunk id = (nb*KB + kb)*64 + l, KB = K/32.

// ============================================================================
// Persistent kernel: all 144 LSTM steps in one launch.
// r5/r6/r7 lesson: FETCH_SIZE stuck at 718 MB = 144 x 5 MB of structurally
// COLD h reads (XCD=nt%8 made every XCD pull all 1 MB of h each step; the
// write-once buffers that guarantee stale-line safety also guarantee zero L2
// reuse). Fix here:
//  - XCD = m-group (bid&7): h rows for group g are produced AND consumed on
//    XCD g -> h loads are local-L2 hits, no cross-XCD h traffic. The %8
//    mapping is a heuristic only -- the RELEASE atomic (buffer_wbl2,
//    writeback-no-invalidate) keeps cross-XCD reads correct if it changes.
//  - Weights become REGISTER-RESIDENT: each wave holds its 80 B-fragments
//    (320 VGPRs) loaded once pre-loop; at s==121 the same storage is
//    reloaded with Wdec fragments. All wB indices are constants after
//    unrolling (enc/dec bodies duplicated) -> no runtime indexing, no spill.
//  - Steady-state beyond-L2 traffic/step ~ 0.
// All 256 blocks co-resident (1 block/CU via 96KB LDS + launch_bounds).
// ============================================================================
__global__ __launch_bounds__(256, 1) void lstm_persist(
    const bf16_t* __restrict__ srcbf,   // (S, B, DP) bf16
    const bf16_t* __restrict__ WcatSw,  // swizzled, KB=40 (src kb 0..7, h kb 8..39)
    const bf16_t* __restrict__ WdecSw,  // swizzled, KB=32
    const float* __restrict__ biasE,
    const float* __restrict__ biasD,
    bf16_t* __restrict__ Hsteps,        // (144, B, H) per-step h (write-once)
    int* __restrict__ bars)             // [144][8] arrival counters (zeroed)
{
  __shared__ Smem sm;
  const int t    = threadIdx.x;
  const int bid  = blockIdx.x;
  const int gI   = bid & 7;          // m-group == XCD (id%8 heuristic)
  const int nt   = bid >> 3;         // n-tile 0..31
  const int m0   = gI * BM;
  const int n0   = nt * BN;
  const int lane = t & 63;
  const int wv   = t >> 6;
  const int fr   = lane & 15;
  const int fq   = lane >> 4;
  const int u0   = n0 >> 2;
  const size_t BH = (size_t)B_SZ * H_SZ;

  // Bias registers (both variants)
  float bE[2], bD[2];
#pragma unroll
  for (int nj = 0; nj < 2; ++nj) {
    int col = n0 + wv * 32 + nj * 16 + fr;
    bE[nj] = biasE[col];
    bD[nj] = biasD[col];
  }

  // Cell state in registers: thread t owns (row = itc*8 + (t>>5), unit u0+(t&31))
  float creg[8];
#pragma unroll
  for (int i = 0; i < 8; ++i) creg[i] = 0.f;

  const int nb0  = (n0 >> 4) + wv * 2;
  const int row8 = t >> 3;
  const int c16s = t & 7;

  // ---- persistent register-resident B fragments (320 VGPRs) ----
  // enc: wB[kb 0..39][nj]; after s==120 reloaded with dec wB[kb 0..31][nj].
  bf16x8 wB[40][2];
  {
    const bf16_t* Wb = WcatSw + (size_t)nb0 * 40 * 512;
#pragma unroll
    for (int kb = 0; kb < 40; ++kb) {
#pragma unroll
      for (int nj = 0; nj < 2; ++nj)
        wB[kb][nj] = *(const bf16x8*)(Wb + ((size_t)nj * 40 + kb) * 512 + lane * 8);
    }
  }

  // A staging with XOR swizzle; LDS dest is wave-uniform base + lane*16.
  auto stageA = [&](const bf16_t* Ap, int sA, int buf, int k0, int nseg) {
    char* base = (char*)&sm.bufs[0][0] + buf * 49152;
#pragma unroll
    for (int half = 0; half < 2; ++half) {
      int row = half * 32 + row8;
      int gc  = (c16s ^ (row & 7)) * 8;
      const bf16_t* ga = Ap + (size_t)(m0 + row) * sA + k0 + gc;
      char* ldst = base + (half * 32 + wv * 8) * 128;
      for (int seg = 0; seg < nseg; ++seg)
        gload16(ga + seg * 64, ldst + seg * 8192);
    }
  };

  f32x4 acc[4][2];

  // one BK-iter: A from LDS(buf,seg), B from persistent regs wB[kb0..kb0+1].
  // kb0 is always a compile-time constant after unrolling.
  auto computeIt = [&](int buf, int seg, int kb0) {
    const char* base = (const char*)&sm.bufs[0][0] + buf * 49152 + seg * 8192;
#pragma unroll
    for (int kk = 0; kk < 2; ++kk)
#pragma unroll
      for (int mi = 0; mi < 4; ++mi) {
        int row = mi * 16 + fr;
        bf16x8 av = *(const bf16x8*)(base + row * 128 +
                                     (((kk * 4 + fq) ^ (row & 7)) * 16));
        acc[mi][0] = __builtin_amdgcn_mfma_f32_16x16x32_bf16(av, wB[kb0 + kk][0], acc[mi][0], 0, 0, 0);
        acc[mi][1] = __builtin_amdgcn_mfma_f32_16x16x32_bf16(av, wB[kb0 + kk][1], acc[mi][1], 0, 0, 0);
      }
  };

  for (int s = 0; s < 144; ++s) {
    const bool enc = (s <= 120);

    if (s == 121) {
      // One-time swap: decoder weights into the same register storage.
      const bf16_t* Wb = WdecSw + (size_t)nb0 * 32 * 512;
#pragma unroll
      for (int kb = 0; kb < 32; ++kb) {
#pragma unroll
        for (int nj = 0; nj < 2; ++nj)
          wB[kb][nj] = *(const bf16x8*)(Wb + ((size_t)nj * 32 + kb) * 512 + lane * 8);
      }
    }

    const float* b2v = enc ? bE : bD;
    bf16_t* hw = Hsteps + (size_t)s * BH;            // write-once per step
    const bf16_t* hr = Hsteps + (size_t)(s - 1) * BH;

#pragma unroll
    for (int mi = 0; mi < 4; ++mi)
#pragma unroll
      for (int nj = 0; nj < 2; ++nj)
        acc[mi][nj] = f32x4{0.f, 0.f, 0.f, 0.f};

    if (enc) {
      // src phase (no h dependency): kb 0..7, iters 0..3 on buf0 segs 0..3
      int xi = (s <= 119) ? s : 119;
      const bf16_t* As = srcbf + (size_t)xi * B_SZ * DP;
      stageA(As, DP, 0, 0, 4);
      __syncthreads();
#pragma unroll
      for (int i = 0; i < 4; ++i) computeIt(0, i, 2 * i);
    }

    if (s > 0) {
      // Wait for all 32 same-group producers of step s-1 (same XCD under
      // the expected mapping -> fast local propagation).
      if (t == 0) {
        while (__hip_atomic_load(&bars[(s - 1) * 8 + gI], __ATOMIC_RELAXED,
                                 __HIP_MEMORY_SCOPE_AGENT) < 32)
          __builtin_amdgcn_s_sleep(1);
      }
      __syncthreads();
      // h phase: 16 iters, staged 6(buf1)/6(buf0)/4(buf1); h is local-L2.
      stageA(hr, H_SZ, 1, 0, 6);
      __syncthreads();
      stageA(hr, H_SZ, 0, 384, 6);
      if (enc) {
#pragma unroll
        for (int i = 0; i < 6; ++i) computeIt(1, i, 8 + 2 * i);
        __syncthreads();
        stageA(hr, H_SZ, 1, 768, 4);
#pragma unroll
        for (int i = 0; i < 6; ++i) computeIt(0, i, 20 + 2 * i);
        __syncthreads();
#pragma unroll
        for (int i = 0; i < 4; ++i) computeIt(1, i, 32 + 2 * i);
      } else {
#pragma unroll
        for (int i = 0; i < 6; ++i) computeIt(1, i, 2 * i);
        __syncthreads();
        stageA(hr, H_SZ, 1, 768, 4);
#pragma unroll
        for (int i = 0; i < 6; ++i) computeIt(0, i, 12 + 2 * i);
        __syncthreads();
#pragma unroll
        for (int i = 0; i < 4; ++i) computeIt(1, i, 24 + 2 * i);
      }
    }

    // ---- epilogue: gates -> LDS (over buf1), cell math, write h ----
    __syncthreads();
#pragma unroll
    for (int mi = 0; mi < 4; ++mi)
#pragma unroll
      for (int nj = 0; nj < 2; ++nj)
#pragma unroll
        for (int v = 0; v < 4; ++v) {
          int row = mi * 16 + fq * 4 + v;
          int col = wv * 32 + nj * 16 + fr;
          sm.g.gate[row * 132 + col] = acc[mi][nj][v] + b2v[nj];
        }
    __syncthreads();
#pragma unroll
    for (int itc = 0; itc < 8; ++itc) {
      int brw = itc * 8 + (t >> 5);
      int ju  = t & 31;
      float4 g4 = *(const float4*)(&sm.g.gate[brw * 132 + ju * 4]);
      float iv = fsigmoid(g4.x);
      float fv = fsigmoid(g4.y);
      float gv = ftanh(g4.z);
      float ov = fsigmoid(g4.w);
      float cn = fv * creg[itc] + iv * gv;
      creg[itc] = cn;
      hw[(size_t)(m0 + brw) * H_SZ + (u0 + ju)] = (bf16_t)(ov * ftanh(cn));
    }
    // syncthreads drains all waves' vmcnt (h stores in L2); the RELEASE
    // atomic then emits s_waitcnt + buffer_wbl2 (write-back, NO invalidate)
    // -- keeps correctness even if block->XCD mapping differs from id%8.
    __syncthreads();
    if (t == 0)
      __hip_atomic_fetch_add(&bars[s * 8 + gI], 1, __ATOMIC_RELEASE,
                             __HIP_MEMORY_SCOPE_AGENT);
  }
}

// ============================================================================
// One-shot GEMM kernel (Wdec build + final projection).
// ============================================================================
template <int EPI, int N1, int N2>
__global__ __launch_bounds__(256, 1) void gemm_step(
    const bf16_t* __restrict__ A1, int sA1,
    const bf16_t* __restrict__ A2, int sA2,
    const bf16_t* __restrict__ Wsw,
    const float* __restrict__ bias,
    const float* __restrict__ addm, bf16_t* __restrict__ outb,
    float* __restrict__ outf)
{
  constexpr int NTOT = N1 + N2;
  constexpr int KB   = NTOT * 2;
  constexpr int C0 = NTOT < 4 ? NTOT : 4;
  constexpr int R0 = NTOT - C0;
  constexpr int C1 = R0 < 6 ? R0 : 6;
  constexpr int R1 = R0 - C1;
  constexpr int C2 = R1 < 6 ? R1 : 6;
  constexpr int C3 = R1 - C2;
  static_assert(C3 <= 6, "chunk overflow");

  __shared__ Smem sm;
  const int t    = threadIdx.x;
  const int m0   = blockIdx.y * BM;
  const int n0   = blockIdx.x * BN;
  const int lane = t & 63;
  const int wv   = t >> 6;
  const int fr   = lane & 15;
  const int fq   = lane >> 4;

  f32x4 acc[4][2] = {};

  float bias2[2] = {0.f, 0.f};
  if (EPI == 3) {
#pragma unroll
    for (int nj = 0; nj < 2; ++nj) {
      int col = n0 + wv * 32 + nj * 16 + fr;
      bias2[nj] = (col >= D_SZ) ? 0.f : bias[col];
    }
  }

  auto stageChunk = [&](int ci, int kst, int csz) {
    const bf16_t* Ap; int sA; int kloc;
    if (ci == 0 && N1 > 0) { Ap = A1; sA = sA1; kloc = 0; }
    else                   { Ap = A2; sA = sA2; kloc = kst - N1 * BK; }
    char* base = (char*)&sm.bufs[ci & 1][0];
    const int row8 = t >> 3;
    const int c16s = (t & 7);
#pragma unroll
    for (int half = 0; half < 2; ++half) {
      int row = half * 32 + row8;
      int gc  = (c16s ^ (row & 7)) * 8;
      const bf16_t* ga = Ap + (size_t)(m0 + row) * sA + kloc + gc;
      char* ldst = base + (half * 32 + wv * 8) * 128;
      for (int seg = 0; seg < csz; ++seg)
        gload16(ga + seg * 64, ldst + seg * 8192);
    }
  };

  const int nb0 = (n0 >> 4) + wv * 2;
  auto loadB = [&](int itq, bf16x8* Bv) {
#pragma unroll
    for (int nj = 0; nj < 2; ++nj)
#pragma unroll
      for (int kk = 0; kk < 2; ++kk)
        Bv[nj * 2 + kk] = *(const bf16x8*)((const char*)Wsw +
            ((size_t)((nb0 + nj) * KB + itq * 2 + kk) * 64 + lane) * 16);
  };

  auto compute = [&](const bf16x8* Bv, int bufi, int seg) {
    const char* base = (const char*)&sm.bufs[bufi][0] + seg * 8192;
#pragma unroll
    for (int kk = 0; kk < 2; ++kk)
#pragma unroll
      for (int mi = 0; mi < 4; ++mi) {
        int row = mi * 16 + fr;
        bf16x8 av = *(const bf16x8*)(base + row * 128 +
                                     (((kk * 4 + fq) ^ (row & 7)) * 16));
        acc[mi][0] = __builtin_amdgcn_mfma_f32_16x16x32_bf16(av, Bv[kk],     acc[mi][0], 0, 0, 0);
        acc[mi][1] = __builtin_amdgcn_mfma_f32_16x16x32_bf16(av, Bv[2 + kk], acc[mi][1], 0, 0, 0);
      }
  };

  bf16x8 Bv[2][4];
  loadB(0, Bv[0]);
  stageChunk(0, 0, C0);
  __syncthreads();
  if (C1 > 0) stageChunk(1, C0 * BK, C1);
#pragma unroll
  for (int i = 0; i < C0; ++i) {
    if (i + 1 < NTOT) loadB(i + 1, Bv[(i + 1) & 1]);
    compute(Bv[i & 1], 0, i);
  }
  if (C1 > 0) {
    __syncthreads();
    if (C2 > 0) stageChunk(2, (C0 + C1) * BK, C2);
#pragma unroll
    for (int i = 0; i < C1; ++i) {
      int itq = C0 + i;
      if (itq + 1 < NTOT) loadB(itq + 1, Bv[(itq + 1) & 1]);
      compute(Bv[itq & 1], 1, i);
    }
  }
  if (C2 > 0) {
    __syncthreads();
    if (C3 > 0) stageChunk(3, (C0 + C1 + C2) * BK, C3);
#pragma unroll
    for (int i = 0; i < C2; ++i) {
      int itq = C0 + C1 + i;
      if (itq + 1 < NTOT) loadB(itq + 1, Bv[(itq + 1) & 1]);
      compute(Bv[itq & 1], 0, i);
    }
  }
  if (C3 > 0) {
    __syncthreads();
#pragma unroll
    for (int i = 0; i < C3; ++i) {
      int itq = C0 + C1 + C2 + i;
      if (itq + 1 < NTOT) loadB(itq + 1, Bv[(itq + 1) & 1]);
      compute(Bv[itq & 1], 1, i);
    }
  }
  __syncthreads();

  if (EPI == 2) {
#pragma unroll
    for (int mi = 0; mi < 4; ++mi)
#pragma unroll
      for (int nj = 0; nj < 2; ++nj)
#pragma unroll
        for (int v = 0; v < 4; ++v) {
          int row = mi * 16 + fq * 4 + v;
          int col = wv * 32 + nj * 16 + fr;
          int gr = m0 + row, gc = n0 + col;
          int orig = (gr & 3) * H_SZ + (gr >> 2);
          sm.g.gate[row * 132 + col] = acc[mi][nj][v] + addm[(size_t)orig * H_SZ + gc];
        }
    __syncthreads();
#pragma unroll
    for (int q = 0; q < 4; ++q) {
      int c = q * 256 + t;
      int nbl = c >> 8, kbl = (c >> 6) & 3, l2 = c & 63;
      int nloc = nbl * 16 + (l2 & 15);
      int kloc = kbl * 32 + (l2 >> 4) * 8;
      const float* gp = &sm.g.gate[nloc * 132 + kloc];
      bf16x8 v;
#pragma unroll
      for (int j = 0; j < 8; ++j) v[j] = (bf16_t)gp[j];
      size_t chunk = (size_t)(((m0 >> 4) + nbl) * 32 + (n0 >> 5) + kbl) * 64 + l2;
      *(bf16x8*)(outb + chunk * 8) = v;
    }
  }

  if (EPI == 3) {
#pragma unroll
    for (int mi = 0; mi < 4; ++mi)
#pragma unroll
      for (int nj = 0; nj < 2; ++nj)
#pragma unroll
        for (int v = 0; v < 4; ++v) {
          int m = m0 + mi * 16 + fq * 4 + v;
          int n = n0 + wv * 32 + nj * 16 + fr;
          if (n < D_SZ) {
            outf[((size_t)(m & 511) * TMAX + (m >> 9)) * D_SZ + n] =
                acc[mi][nj][v] + bias2[nj];
          }
        }
  }
}

// src (B,S,D) fp32 -> srcbf (S,B,DP) bf16, zero-padded
__global__ void k_convert_src(const float* __restrict__ src, bf16_t* __restrict__ dst) {
  int idx = blockIdx.x * 256 + threadIdx.x;
  int total = S_SZ * B_SZ * DP;
  if (idx >= total) return;
  int d = idx % DP;
  int r = idx / DP;
  int b = r % B_SZ;
  int tt = r / B_SZ;
  float v = (d < D_SZ) ? src[((size_t)b * S_SZ + tt) * D_SZ + d] : 0.f;
  dst[idx] = (bf16_t)v;
}

// Swizzled W_cat (N=4096 gate-interleaved rows, K=1280: [Wih|0|Whh]), KB=40
__global__ void k_build_wcat_sw(const float* __restrict__ Wih, const float* __restrict__ Whh,
                                bf16_t* __restrict__ out) {
  int c = blockIdx.x * 256 + threadIdx.x;
  if (c >= 256 * 40 * 64) return;
  int l = c & 63;
  int kb = (c >> 6) % 40;
  int nb = c / (40 * 64);
  int n = nb * 16 + (l & 15);
  int k0 = kb * 32 + (l >> 4) * 8;
  int o = (n & 3) * H_SZ + (n >> 2);
  bf16x8 v;
#pragma unroll
  for (int j = 0; j < 8; ++j) {
    int k = k0 + j;
    float x = (k < D_SZ) ? Wih[(size_t)o * D_SZ + k]
            : (k < DP ? 0.f : Whh[(size_t)o * H_SZ + (k - DP)]);
    v[j] = (bf16_t)x;
  }
  *(bf16x8*)(out + (size_t)c * 8) = v;
}

// Swizzled B for Wdec build: B[n=h][k=d] = Wout[d][h], KB=8
__global__ void k_build_woutt_sw(const float* __restrict__ Wout, bf16_t* __restrict__ out) {
  int c = blockIdx.x * 256 + threadIdx.x;
  if (c >= 64 * 8 * 64) return;
  int l = c & 63;
  int kb = (c >> 6) % 8;
  int nb = c / (8 * 64);
  int n = nb * 16 + (l & 15);
  int k0 = kb * 32 + (l >> 4) * 8;
  bf16x8 v;
#pragma unroll
  for (int j = 0; j < 8; ++j) {
    int k = k0 + j;
    v[j] = (bf16_t)((k < D_SZ) ? Wout[(size_t)k * H_SZ + n] : 0.f);
  }
  *(bf16x8*)(out + (size_t)c * 8) = v;
}

// Swizzled B for final projection: B[n=d][k=h] = Wout[d][h], KB=32
__global__ void k_build_wout_sw(const float* __restrict__ Wout, bf16_t* __restrict__ out) {
  int c = blockIdx.x * 256 + threadIdx.x;
  if (c >= 16 * 32 * 64) return;
  int l = c & 63;
  int kb = (c >> 6) % 32;
  int nb = c / (32 * 64);
  int n = nb * 16 + (l & 15);
  int k0 = kb * 32 + (l >> 4) * 8;
  bf16x8 v;
#pragma unroll
  for (int j = 0; j < 8; ++j)
    v[j] = (bf16_t)((n < D_SZ) ? Wout[(size_t)n * H_SZ + k0 + j] : 0.f);
  *(bf16x8*)(out + (size_t)c * 8) = v;
}

// Natural A for Wdec build: [4096 gate rows][256 d-pad] bf16
__global__ void k_build_wihre(const float* __restrict__ Wih, bf16_t* __restrict__ out) {
  int c = blockIdx.x * 256 + threadIdx.x;
  if (c >= 4096 * 32) return;
  int r = c >> 5;
  int k0 = (c & 31) * 8;
  int o = (r & 3) * H_SZ + (r >> 2);
  bf16x8 v;
#pragma unroll
  for (int j = 0; j < 8; ++j) {
    int k = k0 + j;
    v[j] = (bf16_t)((k < D_SZ) ? Wih[(size_t)o * D_SZ + k] : 0.f);
  }
  *(bf16x8*)(out + (size_t)c * 8) = v;
}

// bias_enc[r] = b_ih[o]+b_hh[o];  bias_dec[r] = bias_enc[r] + W_ih[o,:].b_out
__global__ void k_build_bias(const float* __restrict__ bih, const float* __restrict__ bhh,
                             const float* __restrict__ Wih, const float* __restrict__ bout,
                             float* __restrict__ biasE, float* __restrict__ biasD) {
  int r = blockIdx.x * 256 + threadIdx.x;
  if (r >= NG) return;
  int o = (r & 3) * H_SZ + (r >> 2);
  float be = bih[o] + bhh[o];
  biasE[r] = be;
  float s = 0.f;
  const float* wr = Wih + (size_t)o * D_SZ;
  for (int d = 0; d < D_SZ; ++d) s += wr[d] * bout[d];
  biasD[r] = be + s;
}

extern "C" void kernel_launch(void* const* d_in, const int* in_sizes, int n_in,
                              void* d_out, int out_size, void* d_ws, size_t ws_size,
                              hipStream_t stream) {
  const float* src  = (const float*)d_in[0];
  const float* Wih  = (const float*)d_in[1];
  const float* Whh  = (const float*)d_in[2];
  const float* bih  = (const float*)d_in[3];
  const float* bhh  = (const float*)d_in[4];
  const float* Wout = (const float*)d_in[5];
  const float* bout = (const float*)d_in[6];

  char* ws = (char*)d_ws;
  size_t off = 0;
  auto alloc = [&](size_t bytes) {
    void* p = ws + off;
    off = (off + bytes + 255) & ~(size_t)255;
    return p;
  };
  bf16_t* srcbf  = (bf16_t*)alloc((size_t)S_SZ * B_SZ * DP * 2);   // 31.5 MB
  bf16_t* WcatSw = (bf16_t*)alloc((size_t)256 * 40 * 64 * 16);     // 10.5 MB
  bf16_t* WdecSw = (bf16_t*)alloc((size_t)NG * H_SZ * 2);          //  8.4 MB
  bf16_t* WouttSw= (bf16_t*)alloc((size_t)64 * 8 * 64 * 16);
  bf16_t* WoutSw = (bf16_t*)alloc((size_t)16 * 32 * 64 * 16);
  bf16_t* WihRe  = (bf16_t*)alloc((size_t)NG * DP * 2);            //  2 MB
  float*  biasE  = (float*)alloc((size_t)NG * 4);
  float*  biasD  = (float*)alloc((size_t)NG * 4);
  bf16_t* Hsteps = (bf16_t*)alloc((size_t)144 * B_SZ * H_SZ * 2);  // 151 MB
  int*    bars   = (int*)alloc((size_t)144 * 8 * 4);

  hipMemsetAsync(bars, 0, (size_t)144 * 8 * 4, stream);

  k_convert_src<<<(S_SZ * B_SZ * DP + 255) / 256, 256, 0, stream>>>(src, srcbf);
  k_build_wcat_sw<<<(256 * 40 * 64 + 255) / 256, 256, 0, stream>>>(Wih, Whh, WcatSw);
  k_build_woutt_sw<<<(64 * 8 * 64 + 255) / 256, 256, 0, stream>>>(Wout, WouttSw);
  k_build_wout_sw<<<(16 * 32 * 64 + 255) / 256, 256, 0, stream>>>(Wout, WoutSw);
  k_build_wihre<<<(4096 * 32 + 255) / 256, 256, 0, stream>>>(Wih, WihRe);
  k_build_bias<<<(NG + 255) / 256, 256, 0, stream>>>(bih, bhh, Wih, bout, biasE, biasD);

  // W_dec(swizzled) = Whh_reord + Wih_reord @ Wout  (M=4096, N=1024, K=256)
  gemm_step<2, 4, 0><<<dim3(H_SZ / BN, NG / BM), 256, 0, stream>>>(
      WihRe, DP, nullptr, 0, WouttSw, nullptr, Whh, WdecSw, nullptr);

  // All 144 recurrent steps in one persistent kernel (1D grid: bid&7 = m-group).
  lstm_persist<<<dim3(256), 256, 0, stream>>>(
      srcbf, WcatSw, WdecSw, biasE, biasD, Hsteps, bars);

  // Final projection: Y(12288 x 216) = Hs(12288 x 1024) @ Wout^T + b_out
  // (decoder h = Hsteps slots 120..143, contiguous)
  gemm_step<3, 0, 16><<<dim3(2, (TMAX * B_SZ) / BM), 256, 0, stream>>>(
      nullptr, 0, Hsteps + (size_t)120 * B_SZ * H_SZ, H_SZ, WoutSw, bout,
      nullptr, nullptr, (float*)d_out);
}